// Round 2
// baseline (530.153 us; speedup 1.0000x reference)
//
#include <hip/hip_runtime.h>

// Problem constants
#define E_TOT 8192
#define NB    32
#define H     128
#define EPG   256          // edges per graph (contiguous slots)
#define NDT   34           // 32 edge-attr dims + 1 bias row + 1 root block
#define YD    33           // Y keeps only d<33 (root fused into h)
#define YCOLS (YD * H)     // 4224

typedef __attribute__((ext_vector_type(8))) short bf16x8;
typedef __attribute__((ext_vector_type(4))) float f32x4;

__device__ __forceinline__ unsigned short bf16_rne(float f) {
    unsigned int u = __float_as_uint(f);
    unsigned int r = (u + 0x7FFFu + ((u >> 16) & 1u)) >> 16;
    return (unsigned short)r;
}
__device__ __forceinline__ float bf16_to_f32(unsigned short h) {
    return __uint_as_float(((unsigned int)h) << 16);
}

__device__ __forceinline__ void gload_lds16(const void* g, void* l) {
    __builtin_amdgcn_global_load_lds(
        (const __attribute__((address_space(1))) unsigned int*)g,
        (__attribute__((address_space(3))) unsigned int*)l, 16, 0, 0);
}

// ---------------------------------------------------------------------------
// build_A: A'[v, k'] = [xh | xh | xl] along k' (K'=3*CIN), bf16 bits.
// ---------------------------------------------------------------------------
template<int CIN>
__global__ __launch_bounds__(128)
void build_A(const float* __restrict__ x, unsigned short* __restrict__ A)
{
    const int v = blockIdx.x;
    unsigned short* row = A + (size_t)v * (3 * CIN);
    for (int i = threadIdx.x; i < CIN; i += 128) {
        const float val = x[(size_t)v * CIN + i];
        const unsigned short h = bf16_rne(val);
        const unsigned short l = bf16_rne(val - bf16_to_f32(h));
        row[i] = h; row[CIN + i] = h; row[2 * CIN + i] = l;
    }
}

// ---------------------------------------------------------------------------
// build_Bt: Bt[n, k'] with n = d*128+o (d<32: nn_w, d=32: nn_b, d=33: root),
// k' layout [wh ; wl ; wh]. LDS-transposed so writes are 16B vectors.
// ---------------------------------------------------------------------------
template<int CIN>
__global__ __launch_bounds__(256)
void build_Bt(const float* __restrict__ nnw, const float* __restrict__ nnb,
              const float* __restrict__ root, unsigned short* __restrict__ Bt)
{
    const int d  = blockIdx.x;
    const int i0 = blockIdx.y * 32;
    const float* __restrict__ W =
        (d < 32) ? (nnw + (size_t)d * CIN * 128) : ((d == 32) ? nnb : root);

    __shared__ unsigned short LHI[128][40];
    __shared__ unsigned short LLO[128][40];

    for (int idx = threadIdx.x; idx < 32 * 128; idx += 256) {
        const int ii = idx >> 7, o = idx & 127;
        const float val = W[(size_t)(i0 + ii) * 128 + o];
        const unsigned short h = bf16_rne(val);
        const unsigned short l = bf16_rne(val - bf16_to_f32(h));
        LHI[o][ii] = h; LLO[o][ii] = l;
    }
    __syncthreads();

    const int o    = threadIdx.x & 127;
    const int half = threadIdx.x >> 7;
    unsigned short* dst = Bt + (size_t)(d * 128 + o) * (3 * CIN);
    const uint4* hs = (const uint4*)&LHI[o][0];
    const uint4* ls = (const uint4*)&LLO[o][0];
    if (half == 0) {
        uint4* p = (uint4*)(dst + i0);
        p[0] = hs[0]; p[1] = hs[1]; p[2] = hs[2]; p[3] = hs[3];
        uint4* q = (uint4*)(dst + 2 * CIN + i0);
        q[0] = ls[0]; q[1] = ls[1]; q[2] = ls[2]; q[3] = ls[3];
    } else {
        uint4* p = (uint4*)(dst + CIN + i0);
        p[0] = hs[0]; p[1] = hs[1]; p[2] = hs[2]; p[3] = hs[3];
    }
}

// ---------------------------------------------------------------------------
// fused_stage1: one block per (graph, d-chunk). For each d in the chunk:
//   GEMM 128x128xK (split-bf16 MFMA) -> Ytile(LDS) -> edge contraction into
//   agg(LDS, atomics). Chunk 7 ends with the root job (acc+bias added
//   directly into agg). Flush: atomicAdd agg into h (h pre-zeroed).
// Eliminates the 69 MB Y write + re-read of stage 1 entirely.
// LDS: agg 67.6KB + union{staging 16KB, ytile 67.6KB} = 135KB -> 1 block/CU.
// ---------------------------------------------------------------------------
union YS1 {
    unsigned short stg[2][128 * 32];   // [0]=A-tile, [1]=B-tile staging (16 KB)
    float ytile[128][132];             // 67584 B (pad 132: 16B rows, no 4-way banks)
};

__global__ __launch_bounds__(256, 1)
void fused_stage1(const unsigned short* __restrict__ A,
                  const unsigned short* __restrict__ Bt,
                  const float* __restrict__ ea,
                  const int*   __restrict__ esrc,
                  const int*   __restrict__ edst,
                  const float* __restrict__ bias,
                  float*       __restrict__ hout)
{
    constexpr int K3 = 192;
    __shared__ YS1  ys;
    __shared__ float agg[128][132];

    const int g   = blockIdx.x;        // graph
    const int c   = blockIdx.y;        // d-chunk
    const int tid = threadIdx.x;
    const int lane = tid & 63;
    const int w    = tid >> 6;
    const int wm = w >> 1, wn = w & 1;
    const int arow = lane >> 2;
    const int acol = (lane & 3) * 8;
    const int koff = (lane >> 4) * 8;
    const int mrow = lane & 15;
    const int crow = (lane >> 4) * 4;
    const int ccol = lane & 15;
    const int v0 = g * 128;

    // zero agg (incl. pad); first k-step barrier orders this vs first use
    for (int idx = tid; idx < 128 * 132; idx += 256)
        (&agg[0][0])[idx] = 0.f;

    // chunk job table: chunks 0,1 -> 5 jobs; 2..7 -> 4 jobs; jobs are d=0..33
    const int jb = (c < 2) ? c * 5 : 10 + (c - 2) * 4;
    const int je = jb + ((c < 2) ? 5 : 4);

    for (int d = jb; d < je; ++d) {
        const int n0 = d * 128;

        f32x4 acc[4][4];
        #pragma unroll
        for (int i = 0; i < 4; ++i)
            #pragma unroll
            for (int j = 0; j < 4; ++j)
                acc[i][j] = (f32x4)(0.0f);

        for (int k0 = 0; k0 < K3; k0 += 32) {
            __syncthreads();           // also orders prior edge-pass reads vs staging overwrite
            #pragma unroll
            for (int tt = 0; tt < 2; ++tt) {
                const int cc = w * 2 + tt;
                const int r = cc * 16 + arow;
                gload_lds16(A  + (size_t)(v0 + r) * K3 + k0 + acol, &ys.stg[0][cc * 512]);
                gload_lds16(Bt + (size_t)(n0 + r) * K3 + k0 + acol, &ys.stg[1][cc * 512]);
            }
            __syncthreads();

            bf16x8 a[4], b[4];
            #pragma unroll
            for (int f = 0; f < 4; ++f) {
                a[f] = *(const bf16x8*)&ys.stg[0][(wm * 64 + f * 16 + mrow) * 32 + koff];
                b[f] = *(const bf16x8*)&ys.stg[1][(wn * 64 + f * 16 + mrow) * 32 + koff];
            }
            #pragma unroll
            for (int fm = 0; fm < 4; ++fm)
                #pragma unroll
                for (int fn = 0; fn < 4; ++fn)
                    acc[fm][fn] = __builtin_amdgcn_mfma_f32_16x16x32_bf16(
                        a[fm], b[fn], acc[fm][fn], 0, 0, 0);
        }
        __syncthreads();               // staging reads done before ytile overwrite

        if (d == YD) {
            // root job (always last in its chunk): agg += acc + bias, non-atomic
            #pragma unroll
            for (int fm = 0; fm < 4; ++fm) {
                const int rr = wm * 64 + fm * 16 + crow;
                #pragma unroll
                for (int fn = 0; fn < 4; ++fn) {
                    const int col = wn * 64 + fn * 16 + ccol;
                    const float bv = bias[col];
                    #pragma unroll
                    for (int r = 0; r < 4; ++r)
                        agg[rr + r][col] += acc[fm][fn][r] + bv;
                }
            }
            __syncthreads();
            continue;
        }

        // write acc -> ytile
        #pragma unroll
        for (int fm = 0; fm < 4; ++fm) {
            const int rr = wm * 64 + fm * 16 + crow;
            #pragma unroll
            for (int fn = 0; fn < 4; ++fn) {
                const int col = wn * 64 + fn * 16 + ccol;
                #pragma unroll
                for (int r = 0; r < 4; ++r)
                    ys.ytile[rr + r][col] = acc[fm][fn][r];
            }
        }
        __syncthreads();

        // edge contraction for this d: 8 groups x 32 lanes, 32 edges/group
        const int grp = tid >> 5;
        const int l5  = tid & 31;
        for (int i = grp; i < EPG; i += 8) {
            const int e = g * EPG + i;
            const int s = esrc[e];
            if (s < 0) continue;
            const int sl = s - v0;
            const int dl = edst[e] - v0;
            const float cf = (d == 32) ? 1.0f : ea[(size_t)e * 32 + d];
            const float4 y = *(const float4*)&ys.ytile[sl][l5 * 4];
            atomicAdd(&agg[dl][l5 * 4 + 0], cf * y.x);
            atomicAdd(&agg[dl][l5 * 4 + 1], cf * y.y);
            atomicAdd(&agg[dl][l5 * 4 + 2], cf * y.z);
            atomicAdd(&agg[dl][l5 * 4 + 3], cf * y.w);
        }
        __syncthreads();
    }

    // flush agg -> h (one atomicAdd per element per chunk; h pre-zeroed)
    for (int idx = tid; idx < 128 * 128; idx += 256) {
        const int r = idx >> 7, col = idx & 127;
        atomicAdd(&hout[(size_t)(v0 + r) * H + col], agg[r][col]);
    }
}

// ---------------------------------------------------------------------------
// ygemm_mfma: 128x128 bf16-MFMA tile of A'[M,K3] @ Bt'[N,K3]^T. (stages 2,3)
// ---------------------------------------------------------------------------
template<int K3>
__global__ __launch_bounds__(256)
void ygemm_mfma(const unsigned short* __restrict__ A,
                const unsigned short* __restrict__ Bt,
                float* __restrict__ Y,
                const float* __restrict__ bias,
                float* __restrict__ h)
{
    __shared__ unsigned short Alds[128 * 32];
    __shared__ unsigned short Blds[128 * 32];

    const int lane = threadIdx.x & 63;
    const int w    = threadIdx.x >> 6;
    const int wm = w >> 1, wn = w & 1;
    const int v0 = blockIdx.x * 128;
    const int n0 = blockIdx.y * 128;

    f32x4 acc[4][4];
    #pragma unroll
    for (int i = 0; i < 4; ++i)
        #pragma unroll
        for (int j = 0; j < 4; ++j)
            acc[i][j] = (f32x4)(0.0f);

    const int arow = lane >> 2;
    const int acol = (lane & 3) * 8;
    const int koff = (lane >> 4) * 8;
    const int mrow = lane & 15;

    for (int k0 = 0; k0 < K3; k0 += 32) {
        __syncthreads();
        #pragma unroll
        for (int t = 0; t < 2; ++t) {
            const int c = w * 2 + t;
            const int r = c * 16 + arow;
            gload_lds16(A  + (size_t)(v0 + r) * K3 + k0 + acol, &Alds[c * 512]);
            gload_lds16(Bt + (size_t)(n0 + r) * K3 + k0 + acol, &Blds[c * 512]);
        }
        __syncthreads();

        bf16x8 a[4], b[4];
        #pragma unroll
        for (int f = 0; f < 4; ++f) {
            a[f] = *(const bf16x8*)&Alds[(wm * 64 + f * 16 + mrow) * 32 + koff];
            b[f] = *(const bf16x8*)&Blds[(wn * 64 + f * 16 + mrow) * 32 + koff];
        }
        #pragma unroll
        for (int fm = 0; fm < 4; ++fm)
            #pragma unroll
            for (int fn = 0; fn < 4; ++fn)
                acc[fm][fn] = __builtin_amdgcn_mfma_f32_16x16x32_bf16(
                    a[fm], b[fn], acc[fm][fn], 0, 0, 0);
    }

    const int crow = (lane >> 4) * 4;
    const int ccol = lane & 15;
    const bool is_root = (blockIdx.y == YD);
    #pragma unroll
    for (int fm = 0; fm < 4; ++fm) {
        const int gr = v0 + wm * 64 + fm * 16 + crow;
        #pragma unroll
        for (int fn = 0; fn < 4; ++fn) {
            const int col = wn * 64 + fn * 16 + ccol;   // 0..127 within d-block
            if (is_root) {
                const float bv = bias[col];
                #pragma unroll
                for (int r = 0; r < 4; ++r)
                    h[(size_t)(gr + r) * H + col] = acc[fm][fn][r] + bv;
            } else {
                const size_t gc = (size_t)blockIdx.y * H + col;
                #pragma unroll
                for (int r = 0; r < 4; ++r)
                    Y[(size_t)(gr + r) * YCOLS + gc] = acc[fm][fn][r];
            }
        }
    }
}

// ---------------------------------------------------------------------------
// contract_edges: h[dst[e], :] += sum_{d<32} ea[e,d]*Y[src[e],d,:] + Y[src[e],32,:]
// ---------------------------------------------------------------------------
__global__ __launch_bounds__(256)
void contract_edges(const float* __restrict__ Y,
                    const float* __restrict__ ea,
                    const int*   __restrict__ esrc,
                    const int*   __restrict__ edst,
                    float*       __restrict__ agg)
{
    const int grp = threadIdx.x >> 5;          // 8 groups per block
    const int l5  = threadIdx.x & 31;
    const int e   = blockIdx.x * 8 + grp;
    const int s   = esrc[e];
    if (s < 0) return;

    const float* yb  = Y + (size_t)s * YCOLS + l5 * 4;
    const float* ear = ea + (size_t)e * 32;

    float4 acc = *reinterpret_cast<const float4*>(yb + 32 * H);   // bias row, coef 1
    #pragma unroll 8
    for (int dd = 0; dd < 32; ++dd) {
        const float c = ear[dd];
        const float4 y = *reinterpret_cast<const float4*>(yb + dd * H);
        acc.x += c * y.x; acc.y += c * y.y; acc.z += c * y.z; acc.w += c * y.w;
    }
    float* out = agg + (size_t)edst[e] * H + l5 * 4;
    atomicAdd(out + 0, acc.x);
    atomicAdd(out + 1, acc.y);
    atomicAdd(out + 2, acc.z);
    atomicAdd(out + 3, acc.w);
}

// Column sums / sumsq over n rows of raw h, atomically accumulated.
__global__ __launch_bounds__(256)
void bn_stats(const float* __restrict__ h, int n,
              float* __restrict__ gsum, float* __restrict__ gsumsq)
{
    const int tid   = threadIdx.x;
    const int col   = tid & 127;
    const int rhalf = tid >> 7;
    float s = 0.f, sq = 0.f;
    for (int r = blockIdx.x * 2 + rhalf; r < n; r += gridDim.x * 2) {
        float v = h[(size_t)r * H + col];
        s += v; sq += v * v;
    }
    __shared__ float sh[256];
    sh[tid] = s;  __syncthreads();
    if (rhalf == 0) s += sh[tid + 128];
    __syncthreads();
    sh[tid] = sq; __syncthreads();
    if (rhalf == 0) {
        sq += sh[tid + 128];
        atomicAdd(&gsum[col], s);
        atomicAdd(&gsumsq[col], sq);
    }
}

// ---------------------------------------------------------------------------
// fused_pool: BN + ReLU + score + top-k + next-stage A' emission + edge remap.
// ---------------------------------------------------------------------------
__global__ __launch_bounds__(256)
void fused_pool(const float* __restrict__ h,
                const float* __restrict__ gsum, const float* __restrict__ gsumsq,
                float n_f,
                const float* __restrict__ gamma, const float* __restrict__ beta,
                const float* __restrict__ pw,
                int npg, int k,
                const int* __restrict__ esrc_in, const int* __restrict__ edst_in,
                int* __restrict__ esrc_out, int* __restrict__ edst_out,
                unsigned short* __restrict__ Aout)   // [NB*k, 384]
{
    const int g   = blockIdx.x;
    const int tid = threadIdx.x;
    const int wv  = tid >> 6;
    const int ln  = tid & 63;

    __shared__ float muL[128], rsL[128], gmL[128], btL[128], pwL[128];
    __shared__ float scoreL[128], red[128];
    __shared__ int   mapL[128];
    __shared__ float sinv;

    if (tid < 128) {
        const float mu  = gsum[tid] / n_f;
        const float var = gsumsq[tid] / n_f - mu * mu;
        muL[tid] = mu;
        rsL[tid] = rsqrtf(var + 1e-5f);
        gmL[tid] = gamma[tid];
        btL[tid] = beta[tid];
        const float p = pw[tid];
        pwL[tid] = p;
        red[tid] = p * p;
    }
    __syncthreads();
    for (int off = 64; off > 0; off >>= 1) {
        if (tid < off) red[tid] += red[tid + off];
        __syncthreads();
    }
    if (tid == 0) sinv = rsqrtf(red[0]);
    __syncthreads();

    for (int r = wv; r < npg; r += 4) {
        const float* hr = h + (size_t)(g * npg + r) * H;
        float p = 0.f;
        #pragma unroll
        for (int half = 0; half < 2; ++half) {
            const int c = ln + half * 64;
            const float y = fmaxf(gmL[c] * (hr[c] - muL[c]) * rsL[c] + btL[c], 0.f);
            p += y * pwL[c];
        }
        #pragma unroll
        for (int off = 32; off > 0; off >>= 1)
            p += __shfl_down(p, off, 64);
        if (ln == 0) scoreL[r] = tanhf(p * sinv);
    }
    __syncthreads();

    if (tid < npg) {
        const float si = scoreL[tid];
        int cnt = 0;
        for (int j = 0; j < npg; ++j) {
            const float sj = scoreL[j];
            cnt += (sj > si) || (sj == si && j < tid);
        }
        mapL[tid] = (cnt < k) ? cnt : -1;
    }
    __syncthreads();

    for (int r = wv; r < npg; r += 4) {
        const int nr = mapL[r];
        if (nr < 0) continue;
        const float sc = scoreL[r];
        const float* hr = h + (size_t)(g * npg + r) * H;
        unsigned short* arow = Aout + (size_t)(g * k + nr) * 384;
        #pragma unroll
        for (int half = 0; half < 2; ++half) {
            const int c = ln + half * 64;
            const float y = fmaxf(gmL[c] * (hr[c] - muL[c]) * rsL[c] + btL[c], 0.f) * sc;
            const unsigned short hb = bf16_rne(y);
            const unsigned short lb = bf16_rne(y - bf16_to_f32(hb));
            arow[c] = hb; arow[128 + c] = hb; arow[256 + c] = lb;
        }
    }

    {
        const int e = g * EPG + tid;   // tid in [0,256)
        const int s = esrc_in[e];
        int ns = -1, nd = -1;
        if (s >= 0) {
            const int ms = mapL[s - g * npg];
            const int md = mapL[edst_in[e] - g * npg];
            if (ms >= 0 && md >= 0) { ns = g * k + ms; nd = g * k + md; }
        }
        esrc_out[e] = ns; edst_out[e] = nd;
    }
}

// ---------------------------------------------------------------------------
// fused_pool_final: stage-3 pool (npg=32,k=16) + mean-pool + MLP + sigmoid.
// ---------------------------------------------------------------------------
__global__ __launch_bounds__(256)
void fused_pool_final(const float* __restrict__ h,
                      const float* __restrict__ gsum, const float* __restrict__ gsumsq,
                      float n_f,
                      const float* __restrict__ gamma, const float* __restrict__ beta,
                      const float* __restrict__ pw,
                      const float* __restrict__ lin1_w, const float* __restrict__ lin1_b,
                      const float* __restrict__ lin2_w, const float* __restrict__ lin2_b,
                      float* __restrict__ out)
{
    const int g   = blockIdx.x;
    const int tid = threadIdx.x;
    const int wv  = tid >> 6;
    const int ln  = tid & 63;
    const int npg = 32, k = 16;

    __shared__ float muL[128], rsL[128], gmL[128], btL[128], pwL[128];
    __shared__ float scoreL[32], red[128], gmean[128], h1c[64];
    __shared__ int   mapL[32];
    __shared__ float sinv;

    if (tid < 128) {
        const float mu  = gsum[tid] / n_f;
        const float var = gsumsq[tid] / n_f - mu * mu;
        muL[tid] = mu;
        rsL[tid] = rsqrtf(var + 1e-5f);
        gmL[tid] = gamma[tid];
        btL[tid] = beta[tid];
        const float p = pw[tid];
        pwL[tid] = p;
        red[tid] = p * p;
    }
    __syncthreads();
    for (int off = 64; off > 0; off >>= 1) {
        if (tid < off) red[tid] += red[tid + off];
        __syncthreads();
    }
    if (tid == 0) sinv = rsqrtf(red[0]);
    __syncthreads();

    for (int r = wv; r < npg; r += 4) {
        const float* hr = h + (size_t)(g * npg + r) * H;
        float p = 0.f;
        #pragma unroll
        for (int half = 0; half < 2; ++half) {
            const int c = ln + half * 64;
            const float y = fmaxf(gmL[c] * (hr[c] - muL[c]) * rsL[c] + btL[c], 0.f);
            p += y * pwL[c];
        }
        #pragma unroll
        for (int off = 32; off > 0; off >>= 1)
            p += __shfl_down(p, off, 64);
        if (ln == 0) scoreL[r] = tanhf(p * sinv);
    }
    __syncthreads();

    if (tid < npg) {
        const float si = scoreL[tid];
        int cnt = 0;
        for (int j = 0; j < npg; ++j) {
            const float sj = scoreL[j];
            cnt += (sj > si) || (sj == si && j < tid);
        }
        mapL[tid] = (cnt < k) ? cnt : -1;
    }
    __syncthreads();

    if (tid < 128) {
        float acc = 0.f;
        for (int r = 0; r < npg; ++r) {
            if (mapL[r] < 0) continue;
            const float hv = h[(size_t)(g * npg + r) * H + tid];
            const float y  = fmaxf(gmL[tid] * (hv - muL[tid]) * rsL[tid] + btL[tid], 0.f);
            acc += y * scoreL[r];
        }
        gmean[tid] = acc * (1.0f / 16.0f);
    }
    __syncthreads();

    if (tid < 64) {
        float acc = lin1_b[tid];
        for (int o = 0; o < 128; ++o) acc += gmean[o] * lin1_w[o * 64 + tid];
        h1c[tid] = fmaxf(acc, 0.f);
    }
    __syncthreads();
    if (tid == 0) {
        float z = lin2_b[0];
        for (int j = 0; j < 64; ++j) z += h1c[j] * lin2_w[j];
        out[g] = 1.0f / (1.0f + expf(-z));
    }
}

extern "C" void kernel_launch(void* const* d_in, const int* in_sizes, int n_in,
                              void* d_out, int out_size, void* d_ws, size_t ws_size,
                              hipStream_t stream)
{
    const float* x        = (const float*)d_in[0];
    const int*   ei       = (const int*)  d_in[1];
    const float* eattr    = (const float*)d_in[2];
    const float* nn1_w    = (const float*)d_in[4];
    const float* nn1_b    = (const float*)d_in[5];
    const float* root1    = (const float*)d_in[6];
    const float* bias1    = (const float*)d_in[7];
    const float* nn2_w    = (const float*)d_in[8];
    const float* nn2_b    = (const float*)d_in[9];
    const float* root2    = (const float*)d_in[10];
    const float* bias2    = (const float*)d_in[11];
    const float* nn3_w    = (const float*)d_in[12];
    const float* nn3_b    = (const float*)d_in[13];
    const float* root3    = (const float*)d_in[14];
    const float* bias3    = (const float*)d_in[15];
    const float* gamma1   = (const float*)d_in[16];
    const float* beta1    = (const float*)d_in[17];
    const float* gamma2   = (const float*)d_in[18];
    const float* beta2    = (const float*)d_in[19];
    const float* gamma3   = (const float*)d_in[20];
    const float* beta3    = (const float*)d_in[21];
    const float* pw1      = (const float*)d_in[22];
    const float* pw2      = (const float*)d_in[23];
    const float* pw3      = (const float*)d_in[24];
    const float* lin1_w   = (const float*)d_in[25];
    const float* lin1_b   = (const float*)d_in[26];
    const float* lin2_w   = (const float*)d_in[27];
    const float* lin2_b   = (const float*)d_in[28];

    const int* ei_src = ei;
    const int* ei_dst = ei + E_TOT;

    char* wp = (char*)d_ws;
    auto alloc = [&](size_t bytes) { char* p = wp; wp += (bytes + 255) & ~(size_t)255; return p; };
    float* h1   = (float*)alloc(4096 * 128 * 4);
    float* h2   = (float*)alloc(2048 * 128 * 4);
    float* h3   = (float*)alloc(1024 * 128 * 4);
    int*   src1 = (int*)alloc(E_TOT * 4);
    int*   dst1 = (int*)alloc(E_TOT * 4);
    int*   src2 = (int*)alloc(E_TOT * 4);
    int*   dst2 = (int*)alloc(E_TOT * 4);
    float* stats = (float*)alloc(6 * 128 * 4);
    unsigned short* A1  = (unsigned short*)alloc((size_t)4096 * 192 * 2);
    unsigned short* A2  = (unsigned short*)alloc((size_t)2048 * 384 * 2);
    unsigned short* A3  = (unsigned short*)alloc((size_t)1024 * 384 * 2);
    unsigned short* Bt1 = (unsigned short*)alloc((size_t)4352 * 192 * 2);
    unsigned short* Bt2 = (unsigned short*)alloc((size_t)4352 * 384 * 2);
    unsigned short* Bt3 = (unsigned short*)alloc((size_t)4352 * 384 * 2);
    float* Ybuf = (float*)alloc((size_t)4096 * YCOLS * 4);   // stages 2,3 only now

    hipMemsetAsync(stats, 0, 6 * 128 * sizeof(float), stream);
    hipMemsetAsync(h1, 0, 4096 * 128 * sizeof(float), stream);   // fused_stage1 accumulates

    // Weight preprocessing
    build_Bt<64> <<<dim3(NDT, 2), 256, 0, stream>>>(nn1_w, nn1_b, root1, Bt1);
    build_Bt<128><<<dim3(NDT, 4), 256, 0, stream>>>(nn2_w, nn2_b, root2, Bt2);
    build_Bt<128><<<dim3(NDT, 4), 256, 0, stream>>>(nn3_w, nn3_b, root3, Bt3);
    build_A<64><<<4096, 128, 0, stream>>>(x, A1);

    // ---- Stage 1 (fused GEMM + edge contraction, no Y round-trip) ----
    fused_stage1<<<dim3(NB, 8), 256, 0, stream>>>(A1, Bt1, eattr, ei_src, ei_dst,
                                                  bias1, h1);
    bn_stats<<<64, 256, 0, stream>>>(h1, 4096, stats, stats + 128);
    fused_pool<<<NB, 256, 0, stream>>>(h1, stats, stats + 128, 4096.0f,
                                       gamma1, beta1, pw1, 128, 64,
                                       ei_src, ei_dst, src1, dst1, A2);

    // ---- Stage 2 ----
    ygemm_mfma<384><<<dim3(16, NDT), 256, 0, stream>>>(A2, Bt2, Ybuf, bias2, h2);
    contract_edges<<<E_TOT / 8, 256, 0, stream>>>(Ybuf, eattr, src1, dst1, h2);
    bn_stats<<<64, 256, 0, stream>>>(h2, 2048, stats + 256, stats + 384);
    fused_pool<<<NB, 256, 0, stream>>>(h2, stats + 256, stats + 384, 2048.0f,
                                       gamma2, beta2, pw2, 64, 32,
                                       src1, dst1, src2, dst2, A3);

    // ---- Stage 3 ----
    ygemm_mfma<384><<<dim3(8, NDT), 256, 0, stream>>>(A3, Bt3, Ybuf, bias3, h3);
    contract_edges<<<E_TOT / 8, 256, 0, stream>>>(Ybuf, eattr, src2, dst2, h3);
    bn_stats<<<64, 256, 0, stream>>>(h3, 1024, stats + 512, stats + 640);
    fused_pool_final<<<NB, 256, 0, stream>>>(h3, stats + 512, stats + 640, 1024.0f,
                                             gamma3, beta3, pw3,
                                             lin1_w, lin1_b, lin2_w, lin2_b,
                                             (float*)d_out);
}

// Round 3
// 435.819 us; speedup vs baseline: 1.2165x; 1.2165x over previous
//
#include <hip/hip_runtime.h>

// Problem constants
#define E_TOT 8192
#define NB    32
#define H     128
#define EPG   256          // edges per graph (contiguous slots)
#define NDT   34           // 32 edge-attr dims + 1 bias row + 1 root block
#define YD    33           // Y keeps only d<33 (root fused into h)
#define YCOLS (YD * H)     // 4224

// Stage-1 T-GEMM geometry: K = 33*64 (msg) + 64 (root) = 2176
#define KH1   2176
#define TROW1 (2 * KH1)    // [Th | Tl] per row = 4352 shorts

typedef __attribute__((ext_vector_type(8))) short bf16x8;
typedef __attribute__((ext_vector_type(4))) float f32x4;

__device__ __forceinline__ unsigned short bf16_rne(float f) {
    unsigned int u = __float_as_uint(f);
    unsigned int r = (u + 0x7FFFu + ((u >> 16) & 1u)) >> 16;
    return (unsigned short)r;
}
__device__ __forceinline__ float bf16_to_f32(unsigned short h) {
    return __uint_as_float(((unsigned int)h) << 16);
}

__device__ __forceinline__ void gload_lds16(const void* g, void* l) {
    __builtin_amdgcn_global_load_lds(
        (const __attribute__((address_space(1))) unsigned int*)g,
        (__attribute__((address_space(3))) unsigned int*)l, 16, 0, 0);
}

// ---------------------------------------------------------------------------
// build_Bt1n: Bt[o, k'] for the stage-1 T-GEMM, k' = [Wh(2176) | Wl(2176)].
// k<2112: (d=k/64, i=k%64) -> nn1_w[d,i,o] (d<32) or nn1_b[i,o] (d==32);
// k in [2112,2176): root1[i,o].  One block per d-slot (34 blocks).
// ---------------------------------------------------------------------------
__global__ __launch_bounds__(256)
void build_Bt1n(const float* __restrict__ nnw, const float* __restrict__ nnb,
                const float* __restrict__ root, unsigned short* __restrict__ Bt)
{
    const int d = blockIdx.x;                       // 0..33
    const float* __restrict__ W =
        (d < 32) ? (nnw + (size_t)d * 8192) : ((d == 32) ? nnb : root);
    const int kbase = d * 64;                       // d=33 -> 2112 (root)

    __shared__ unsigned short LHI[128][72];         // pad 72: 16B-aligned rows
    __shared__ unsigned short LLO[128][72];

    for (int idx = threadIdx.x; idx < 64 * 128; idx += 256) {
        const int ii = idx >> 7, o = idx & 127;
        const float val = W[ii * 128 + o];
        const unsigned short h = bf16_rne(val);
        LHI[o][ii] = h;
        LLO[o][ii] = bf16_rne(val - bf16_to_f32(h));
    }
    __syncthreads();

    const int o    = threadIdx.x & 127;
    const int half = threadIdx.x >> 7;              // 0: hi, 1: lo
    const uint4* s4 = (const uint4*)(half ? &LLO[o][0] : &LHI[o][0]);
    uint4* d4 = (uint4*)(Bt + (size_t)o * TROW1 + (half ? KH1 : 0) + kbase);
    #pragma unroll
    for (int q = 0; q < 8; ++q) d4[q] = s4[q];      // 64 shorts = 128 B
}

// ---------------------------------------------------------------------------
// t1_build: T[u, k'] = [Th | Tl], Th[d*64+i] = sum_{e:dst=u} ea[e,d]*x[src,i]
// (d=32: coefficient 1), Th[2112+i] = x[u,i] (root section).
// Exact f32 aggregation, then hi/lo bf16 split. One block = 32 dst rows of
// one graph; wave-per-row, lane = i, dense edge scan (uniform branch).
// ---------------------------------------------------------------------------
__global__ __launch_bounds__(256)
void t1_build(const float* __restrict__ x, const float* __restrict__ ea,
              const int* __restrict__ esrc, const int* __restrict__ edst,
              unsigned short* __restrict__ T)
{
    const int g   = blockIdx.x;
    const int uc  = blockIdx.y;          // u-chunk of 32 rows
    const int tid = threadIdx.x;
    const int wv  = tid >> 6;
    const int ln  = tid & 63;            // = input-feature i

    __shared__ float xL[128][64];        // 32 KB
    __shared__ float eaL[256][32];       // 32 KB
    __shared__ int   srcL[256], dstL[256];

    for (int idx = tid; idx < 128 * 64; idx += 256)
        xL[idx >> 6][idx & 63] = x[(size_t)g * 8192 + idx];
    for (int idx = tid; idx < 256 * 32; idx += 256)
        eaL[idx >> 5][idx & 31] = ea[(size_t)g * 8192 + idx];
    if (tid < 256) {
        srcL[tid] = esrc[g * EPG + tid] - g * 128;   // local ids (all valid, stage 1)
        dstL[tid] = edst[g * EPG + tid] - g * 128;
    }
    __syncthreads();

    for (int j = 0; j < 8; ++j) {
        const int u = uc * 32 + wv * 8 + j;
        float acc[33];
        #pragma unroll
        for (int d = 0; d < 33; ++d) acc[d] = 0.f;

        for (int e = 0; e < EPG; ++e) {
            if (dstL[e] == u) {          // wave-uniform branch
                const float xv = xL[srcL[e]][ln];
                #pragma unroll
                for (int d = 0; d < 32; ++d) acc[d] += eaL[e][d] * xv;
                acc[32] += xv;           // bias slot, coefficient 1
            }
        }

        unsigned short* row = T + (size_t)(g * 128 + u) * TROW1;
        #pragma unroll
        for (int d = 0; d < 33; ++d) {
            const unsigned short hb = bf16_rne(acc[d]);
            const unsigned short lb = bf16_rne(acc[d] - bf16_to_f32(hb));
            row[d * 64 + ln] = hb;
            row[KH1 + d * 64 + ln] = lb;
        }
        const float xv = xL[u][ln];      // root section
        const unsigned short hb = bf16_rne(xv);
        const unsigned short lb = bf16_rne(xv - bf16_to_f32(hb));
        row[2112 + ln] = hb;
        row[KH1 + 2112 + ln] = lb;
    }
}

// ---------------------------------------------------------------------------
// hgemm1: h1 = T1' @ Bt1'^T directly (no Y, no contract kernel).
// M=4096 (32 tiles), N=128, 204 k-steps in 3 sections:
//   s0: Th*Wh, s1: Th*Wl, s2: Tl*Wh  (split-bf16, same terms as baseline).
// Grid (32, 6): k-split 6 x 34 k-steps; partials atomicAdd into pre-zeroed h1;
// block c==0 adds bias once.
// ---------------------------------------------------------------------------
__global__ __launch_bounds__(256)
void hgemm1(const unsigned short* __restrict__ A,    // T1 [4096][4352]
            const unsigned short* __restrict__ Bt,   // [128][4352]
            const float* __restrict__ bias,
            float* __restrict__ hout)                // [4096][128] pre-zeroed
{
    __shared__ unsigned short Alds[128 * 32];
    __shared__ unsigned short Blds[128 * 32];

    const int lane = threadIdx.x & 63;
    const int w    = threadIdx.x >> 6;
    const int wm = w >> 1, wn = w & 1;
    const int v0 = blockIdx.x * 128;
    const int c  = blockIdx.y;                       // 0..5

    f32x4 acc[4][4];
    #pragma unroll
    for (int i = 0; i < 4; ++i)
        #pragma unroll
        for (int j = 0; j < 4; ++j)
            acc[i][j] = (f32x4)(0.0f);

    const int arow = lane >> 2;
    const int acol = (lane & 3) * 8;
    const int koff = (lane >> 4) * 8;
    const int mrow = lane & 15;

    for (int t = c * 34; t < c * 34 + 34; ++t) {
        const int s  = t / 68;                       // section 0,1,2
        const int ko = (t - s * 68) * 32;
        const int aoff = (s == 2 ? KH1 : 0) + ko;    // s2 reads Tl
        const int boff = (s == 1 ? KH1 : 0) + ko;    // s1 reads Wl

        __syncthreads();
        #pragma unroll
        for (int tt = 0; tt < 2; ++tt) {
            const int cc = w * 2 + tt;
            const int r = cc * 16 + arow;
            gload_lds16(A  + (size_t)(v0 + r) * TROW1 + aoff + acol, &Alds[cc * 512]);
            gload_lds16(Bt + (size_t)r * TROW1 + boff + acol, &Blds[cc * 512]);
        }
        __syncthreads();

        bf16x8 a[4], b[4];
        #pragma unroll
        for (int f = 0; f < 4; ++f) {
            a[f] = *(const bf16x8*)&Alds[(wm * 64 + f * 16 + mrow) * 32 + koff];
            b[f] = *(const bf16x8*)&Blds[(wn * 64 + f * 16 + mrow) * 32 + koff];
        }
        #pragma unroll
        for (int fm = 0; fm < 4; ++fm)
            #pragma unroll
            for (int fn = 0; fn < 4; ++fn)
                acc[fm][fn] = __builtin_amdgcn_mfma_f32_16x16x32_bf16(
                    a[fm], b[fn], acc[fm][fn], 0, 0, 0);
    }

    const int crow = (lane >> 4) * 4;
    const int ccol = lane & 15;
    #pragma unroll
    for (int fm = 0; fm < 4; ++fm) {
        const int gr = v0 + wm * 64 + fm * 16 + crow;
        #pragma unroll
        for (int fn = 0; fn < 4; ++fn) {
            const int col = wn * 64 + fn * 16 + ccol;
            const float bv = (c == 0) ? bias[col] : 0.f;
            #pragma unroll
            for (int r = 0; r < 4; ++r)
                atomicAdd(&hout[(size_t)(gr + r) * H + col], acc[fm][fn][r] + bv);
        }
    }
}

// ---------------------------------------------------------------------------
// build_Bt (stages 2,3 — unchanged baseline)
// ---------------------------------------------------------------------------
template<int CIN>
__global__ __launch_bounds__(256)
void build_Bt(const float* __restrict__ nnw, const float* __restrict__ nnb,
              const float* __restrict__ root, unsigned short* __restrict__ Bt)
{
    const int d  = blockIdx.x;
    const int i0 = blockIdx.y * 32;
    const float* __restrict__ W =
        (d < 32) ? (nnw + (size_t)d * CIN * 128) : ((d == 32) ? nnb : root);

    __shared__ unsigned short LHI[128][40];
    __shared__ unsigned short LLO[128][40];

    for (int idx = threadIdx.x; idx < 32 * 128; idx += 256) {
        const int ii = idx >> 7, o = idx & 127;
        const float val = W[(size_t)(i0 + ii) * 128 + o];
        const unsigned short h = bf16_rne(val);
        const unsigned short l = bf16_rne(val - bf16_to_f32(h));
        LHI[o][ii] = h; LLO[o][ii] = l;
    }
    __syncthreads();

    const int o    = threadIdx.x & 127;
    const int half = threadIdx.x >> 7;
    unsigned short* dst = Bt + (size_t)(d * 128 + o) * (3 * CIN);
    const uint4* hs = (const uint4*)&LHI[o][0];
    const uint4* ls = (const uint4*)&LLO[o][0];
    if (half == 0) {
        uint4* p = (uint4*)(dst + i0);
        p[0] = hs[0]; p[1] = hs[1]; p[2] = hs[2]; p[3] = hs[3];
        uint4* q = (uint4*)(dst + 2 * CIN + i0);
        q[0] = ls[0]; q[1] = ls[1]; q[2] = ls[2]; q[3] = ls[3];
    } else {
        uint4* p = (uint4*)(dst + CIN + i0);
        p[0] = hs[0]; p[1] = hs[1]; p[2] = hs[2]; p[3] = hs[3];
    }
}

// ---------------------------------------------------------------------------
// ygemm_mfma (stages 2,3 — unchanged baseline)
// ---------------------------------------------------------------------------
template<int K3>
__global__ __launch_bounds__(256)
void ygemm_mfma(const unsigned short* __restrict__ A,
                const unsigned short* __restrict__ Bt,
                float* __restrict__ Y,
                const float* __restrict__ bias,
                float* __restrict__ h)
{
    __shared__ unsigned short Alds[128 * 32];
    __shared__ unsigned short Blds[128 * 32];

    const int lane = threadIdx.x & 63;
    const int w    = threadIdx.x >> 6;
    const int wm = w >> 1, wn = w & 1;
    const int v0 = blockIdx.x * 128;
    const int n0 = blockIdx.y * 128;

    f32x4 acc[4][4];
    #pragma unroll
    for (int i = 0; i < 4; ++i)
        #pragma unroll
        for (int j = 0; j < 4; ++j)
            acc[i][j] = (f32x4)(0.0f);

    const int arow = lane >> 2;
    const int acol = (lane & 3) * 8;
    const int koff = (lane >> 4) * 8;
    const int mrow = lane & 15;

    for (int k0 = 0; k0 < K3; k0 += 32) {
        __syncthreads();
        #pragma unroll
        for (int t = 0; t < 2; ++t) {
            const int c = w * 2 + t;
            const int r = c * 16 + arow;
            gload_lds16(A  + (size_t)(v0 + r) * K3 + k0 + acol, &Alds[c * 512]);
            gload_lds16(Bt + (size_t)(n0 + r) * K3 + k0 + acol, &Blds[c * 512]);
        }
        __syncthreads();

        bf16x8 a[4], b[4];
        #pragma unroll
        for (int f = 0; f < 4; ++f) {
            a[f] = *(const bf16x8*)&Alds[(wm * 64 + f * 16 + mrow) * 32 + koff];
            b[f] = *(const bf16x8*)&Blds[(wn * 64 + f * 16 + mrow) * 32 + koff];
        }
        #pragma unroll
        for (int fm = 0; fm < 4; ++fm)
            #pragma unroll
            for (int fn = 0; fn < 4; ++fn)
                acc[fm][fn] = __builtin_amdgcn_mfma_f32_16x16x32_bf16(
                    a[fm], b[fn], acc[fm][fn], 0, 0, 0);
    }

    const int crow = (lane >> 4) * 4;
    const int ccol = lane & 15;
    const bool is_root = (blockIdx.y == YD);
    #pragma unroll
    for (int fm = 0; fm < 4; ++fm) {
        const int gr = v0 + wm * 64 + fm * 16 + crow;
        #pragma unroll
        for (int fn = 0; fn < 4; ++fn) {
            const int col = wn * 64 + fn * 16 + ccol;   // 0..127 within d-block
            if (is_root) {
                const float bv = bias[col];
                #pragma unroll
                for (int r = 0; r < 4; ++r)
                    h[(size_t)(gr + r) * H + col] = acc[fm][fn][r] + bv;
            } else {
                const size_t gc = (size_t)blockIdx.y * H + col;
                #pragma unroll
                for (int r = 0; r < 4; ++r)
                    Y[(size_t)(gr + r) * YCOLS + gc] = acc[fm][fn][r];
            }
        }
    }
}

// ---------------------------------------------------------------------------
// contract_edges (stages 2,3 — unchanged baseline)
// ---------------------------------------------------------------------------
__global__ __launch_bounds__(256)
void contract_edges(const float* __restrict__ Y,
                    const float* __restrict__ ea,
                    const int*   __restrict__ esrc,
                    const int*   __restrict__ edst,
                    float*       __restrict__ agg)
{
    const int grp = threadIdx.x >> 5;          // 8 groups per block
    const int l5  = threadIdx.x & 31;
    const int e   = blockIdx.x * 8 + grp;
    const int s   = esrc[e];
    if (s < 0) return;

    const float* yb  = Y + (size_t)s * YCOLS + l5 * 4;
    const float* ear = ea + (size_t)e * 32;

    float4 acc = *reinterpret_cast<const float4*>(yb + 32 * H);   // bias row, coef 1
    #pragma unroll 8
    for (int dd = 0; dd < 32; ++dd) {
        const float c = ear[dd];
        const float4 y = *reinterpret_cast<const float4*>(yb + dd * H);
        acc.x += c * y.x; acc.y += c * y.y; acc.z += c * y.z; acc.w += c * y.w;
    }
    float* out = agg + (size_t)edst[e] * H + l5 * 4;
    atomicAdd(out + 0, acc.x);
    atomicAdd(out + 1, acc.y);
    atomicAdd(out + 2, acc.z);
    atomicAdd(out + 3, acc.w);
}

// Column sums / sumsq over n rows of raw h, atomically accumulated.
__global__ __launch_bounds__(256)
void bn_stats(const float* __restrict__ h, int n,
              float* __restrict__ gsum, float* __restrict__ gsumsq)
{
    const int tid   = threadIdx.x;
    const int col   = tid & 127;
    const int rhalf = tid >> 7;
    float s = 0.f, sq = 0.f;
    for (int r = blockIdx.x * 2 + rhalf; r < n; r += gridDim.x * 2) {
        float v = h[(size_t)r * H + col];
        s += v; sq += v * v;
    }
    __shared__ float sh[256];
    sh[tid] = s;  __syncthreads();
    if (rhalf == 0) s += sh[tid + 128];
    __syncthreads();
    sh[tid] = sq; __syncthreads();
    if (rhalf == 0) {
        sq += sh[tid + 128];
        atomicAdd(&gsum[col], s);
        atomicAdd(&gsumsq[col], sq);
    }
}

// ---------------------------------------------------------------------------
// fused_pool: BN + ReLU + score + top-k + next-stage A' emission + edge remap.
// (unchanged baseline)
// ---------------------------------------------------------------------------
__global__ __launch_bounds__(256)
void fused_pool(const float* __restrict__ h,
                const float* __restrict__ gsum, const float* __restrict__ gsumsq,
                float n_f,
                const float* __restrict__ gamma, const float* __restrict__ beta,
                const float* __restrict__ pw,
                int npg, int k,
                const int* __restrict__ esrc_in, const int* __restrict__ edst_in,
                int* __restrict__ esrc_out, int* __restrict__ edst_out,
                unsigned short* __restrict__ Aout)   // [NB*k, 384]
{
    const int g   = blockIdx.x;
    const int tid = threadIdx.x;
    const int wv  = tid >> 6;
    const int ln  = tid & 63;

    __shared__ float muL[128], rsL[128], gmL[128], btL[128], pwL[128];
    __shared__ float scoreL[128], red[128];
    __shared__ int   mapL[128];
    __shared__ float sinv;

    if (tid < 128) {
        const float mu  = gsum[tid] / n_f;
        const float var = gsumsq[tid] / n_f - mu * mu;
        muL[tid] = mu;
        rsL[tid] = rsqrtf(var + 1e-5f);
        gmL[tid] = gamma[tid];
        btL[tid] = beta[tid];
        const float p = pw[tid];
        pwL[tid] = p;
        red[tid] = p * p;
    }
    __syncthreads();
    for (int off = 64; off > 0; off >>= 1) {
        if (tid < off) red[tid] += red[tid + off];
        __syncthreads();
    }
    if (tid == 0) sinv = rsqrtf(red[0]);
    __syncthreads();

    for (int r = wv; r < npg; r += 4) {
        const float* hr = h + (size_t)(g * npg + r) * H;
        float p = 0.f;
        #pragma unroll
        for (int half = 0; half < 2; ++half) {
            const int c = ln + half * 64;
            const float y = fmaxf(gmL[c] * (hr[c] - muL[c]) * rsL[c] + btL[c], 0.f);
            p += y * pwL[c];
        }
        #pragma unroll
        for (int off = 32; off > 0; off >>= 1)
            p += __shfl_down(p, off, 64);
        if (ln == 0) scoreL[r] = tanhf(p * sinv);
    }
    __syncthreads();

    if (tid < npg) {
        const float si = scoreL[tid];
        int cnt = 0;
        for (int j = 0; j < npg; ++j) {
            const float sj = scoreL[j];
            cnt += (sj > si) || (sj == si && j < tid);
        }
        mapL[tid] = (cnt < k) ? cnt : -1;
    }
    __syncthreads();

    for (int r = wv; r < npg; r += 4) {
        const int nr = mapL[r];
        if (nr < 0) continue;
        const float sc = scoreL[r];
        const float* hr = h + (size_t)(g * npg + r) * H;
        unsigned short* arow = Aout + (size_t)(g * k + nr) * 384;
        #pragma unroll
        for (int half = 0; half < 2; ++half) {
            const int c = ln + half * 64;
            const float y = fmaxf(gmL[c] * (hr[c] - muL[c]) * rsL[c] + btL[c], 0.f) * sc;
            const unsigned short hb = bf16_rne(y);
            const unsigned short lb = bf16_rne(y - bf16_to_f32(hb));
            arow[c] = hb; arow[128 + c] = hb; arow[256 + c] = lb;
        }
    }

    {
        const int e = g * EPG + tid;   // tid in [0,256)
        const int s = esrc_in[e];
        int ns = -1, nd = -1;
        if (s >= 0) {
            const int ms = mapL[s - g * npg];
            const int md = mapL[edst_in[e] - g * npg];
            if (ms >= 0 && md >= 0) { ns = g * k + ms; nd = g * k + md; }
        }
        esrc_out[e] = ns; edst_out[e] = nd;
    }
}

// ---------------------------------------------------------------------------
// fused_pool_final: stage-3 pool (npg=32,k=16) + mean-pool + MLP + sigmoid.
// (unchanged baseline)
// ---------------------------------------------------------------------------
__global__ __launch_bounds__(256)
void fused_pool_final(const float* __restrict__ h,
                      const float* __restrict__ gsum, const float* __restrict__ gsumsq,
                      float n_f,
                      const float* __restrict__ gamma, const float* __restrict__ beta,
                      const float* __restrict__ pw,
                      const float* __restrict__ lin1_w, const float* __restrict__ lin1_b,
                      const float* __restrict__ lin2_w, const float* __restrict__ lin2_b,
                      float* __restrict__ out)
{
    const int g   = blockIdx.x;
    const int tid = threadIdx.x;
    const int wv  = tid >> 6;
    const int ln  = tid & 63;
    const int npg = 32, k = 16;

    __shared__ float muL[128], rsL[128], gmL[128], btL[128], pwL[128];
    __shared__ float scoreL[32], red[128], gmean[128], h1c[64];
    __shared__ int   mapL[32];
    __shared__ float sinv;

    if (tid < 128) {
        const float mu  = gsum[tid] / n_f;
        const float var = gsumsq[tid] / n_f - mu * mu;
        muL[tid] = mu;
        rsL[tid] = rsqrtf(var + 1e-5f);
        gmL[tid] = gamma[tid];
        btL[tid] = beta[tid];
        const float p = pw[tid];
        pwL[tid] = p;
        red[tid] = p * p;
    }
    __syncthreads();
    for (int off = 64; off > 0; off >>= 1) {
        if (tid < off) red[tid] += red[tid + off];
        __syncthreads();
    }
    if (tid == 0) sinv = rsqrtf(red[0]);
    __syncthreads();

    for (int r = wv; r < npg; r += 4) {
        const float* hr = h + (size_t)(g * npg + r) * H;
        float p = 0.f;
        #pragma unroll
        for (int half = 0; half < 2; ++half) {
            const int c = ln + half * 64;
            const float y = fmaxf(gmL[c] * (hr[c] - muL[c]) * rsL[c] + btL[c], 0.f);
            p += y * pwL[c];
        }
        #pragma unroll
        for (int off = 32; off > 0; off >>= 1)
            p += __shfl_down(p, off, 64);
        if (ln == 0) scoreL[r] = tanhf(p * sinv);
    }
    __syncthreads();

    if (tid < npg) {
        const float si = scoreL[tid];
        int cnt = 0;
        for (int j = 0; j < npg; ++j) {
            const float sj = scoreL[j];
            cnt += (sj > si) || (sj == si && j < tid);
        }
        mapL[tid] = (cnt < k) ? cnt : -1;
    }
    __syncthreads();

    if (tid < 128) {
        float acc = 0.f;
        for (int r = 0; r < npg; ++r) {
            if (mapL[r] < 0) continue;
            const float hv = h[(size_t)(g * npg + r) * H + tid];
            const float y  = fmaxf(gmL[tid] * (hv - muL[tid]) * rsL[tid] + btL[tid], 0.f);
            acc += y * scoreL[r];
        }
        gmean[tid] = acc * (1.0f / 16.0f);
    }
    __syncthreads();

    if (tid < 64) {
        float acc = lin1_b[tid];
        for (int o = 0; o < 128; ++o) acc += gmean[o] * lin1_w[o * 64 + tid];
        h1c[tid] = fmaxf(acc, 0.f);
    }
    __syncthreads();
    if (tid == 0) {
        float z = lin2_b[0];
        for (int j = 0; j < 64; ++j) z += h1c[j] * lin2_w[j];
        out[g] = 1.0f / (1.0f + expf(-z));
    }
}

extern "C" void kernel_launch(void* const* d_in, const int* in_sizes, int n_in,
                              void* d_out, int out_size, void* d_ws, size_t ws_size,
                              hipStream_t stream)
{
    const float* x        = (const float*)d_in[0];
    const int*   ei       = (const int*)  d_in[1];
    const float* eattr    = (const float*)d_in[2];
    const float* nn1_w    = (const float*)d_in[4];
    const float* nn1_b    = (const float*)d_in[5];
    const float* root1    = (const float*)d_in[6];
    const float* bias1    = (const float*)d_in[7];
    const float* nn2_w    = (const float*)d_in[8];
    const float* nn2_b    = (const float*)d_in[9];
    const float* root2    = (const float*)d_in[10];
    const float* bias2    = (const float*)d_in[11];
    const float* nn3_w    = (const float*)d_in[12];
    const float* nn3_b    = (const float*)d_in[13];
    const float* root3    = (const float*)d_in[14];
    const float* bias3    = (const float*)d_in[15];
    const float* gamma1   = (const float*)d_in[16];
    const float* beta1    = (const float*)d_in[17];
    const float* gamma2   = (const float*)d_in[18];
    const float* beta2    = (const float*)d_in[19];
    const float* gamma3   = (const float*)d_in[20];
    const float* beta3    = (const float*)d_in[21];
    const float* pw1      = (const float*)d_in[22];
    const float* pw2      = (const float*)d_in[23];
    const float* pw3      = (const float*)d_in[24];
    const float* lin1_w   = (const float*)d_in[25];
    const float* lin1_b   = (const float*)d_in[26];
    const float* lin2_w   = (const float*)d_in[27];
    const float* lin2_b   = (const float*)d_in[28];

    const int* ei_src = ei;
    const int* ei_dst = ei + E_TOT;

    char* wp = (char*)d_ws;
    auto alloc = [&](size_t bytes) { char* p = wp; wp += (bytes + 255) & ~(size_t)255; return p; };
    float* h1   = (float*)alloc(4096 * 128 * 4);
    float* h2   = (float*)alloc(2048 * 128 * 4);
    float* h3   = (float*)alloc(1024 * 128 * 4);
    int*   src1 = (int*)alloc(E_TOT * 4);
    int*   dst1 = (int*)alloc(E_TOT * 4);
    int*   src2 = (int*)alloc(E_TOT * 4);
    int*   dst2 = (int*)alloc(E_TOT * 4);
    float* stats = (float*)alloc(6 * 128 * 4);
    unsigned short* A2   = (unsigned short*)alloc((size_t)2048 * 384 * 2);
    unsigned short* A3   = (unsigned short*)alloc((size_t)1024 * 384 * 2);
    unsigned short* Bt1n = (unsigned short*)alloc((size_t)128 * TROW1 * 2);
    unsigned short* Bt2  = (unsigned short*)alloc((size_t)4352 * 384 * 2);
    unsigned short* Bt3  = (unsigned short*)alloc((size_t)4352 * 384 * 2);
    unsigned short* T1   = (unsigned short*)alloc((size_t)4096 * TROW1 * 2);  // 35.7 MB
    float* Ybuf = (float*)alloc((size_t)2048 * YCOLS * 4);   // stages 2,3 only

    hipMemsetAsync(stats, 0, 6 * 128 * sizeof(float), stream);
    hipMemsetAsync(h1, 0, 4096 * 128 * sizeof(float), stream);  // hgemm1 accumulates

    // Weight preprocessing
    build_Bt1n<<<NDT, 256, 0, stream>>>(nn1_w, nn1_b, root1, Bt1n);
    build_Bt<128><<<dim3(NDT, 4), 256, 0, stream>>>(nn2_w, nn2_b, root2, Bt2);
    build_Bt<128><<<dim3(NDT, 4), 256, 0, stream>>>(nn3_w, nn3_b, root3, Bt3);

    // ---- Stage 1: aggregate-first (T1) + dense GEMM straight into h1 ----
    t1_build<<<dim3(NB, 4), 256, 0, stream>>>(x, eattr, ei_src, ei_dst, T1);
    hgemm1<<<dim3(32, 6), 256, 0, stream>>>(T1, Bt1n, bias1, h1);
    bn_stats<<<64, 256, 0, stream>>>(h1, 4096, stats, stats + 128);
    fused_pool<<<NB, 256, 0, stream>>>(h1, stats, stats + 128, 4096.0f,
                                       gamma1, beta1, pw1, 128, 64,
                                       ei_src, ei_dst, src1, dst1, A2);

    // ---- Stage 2 (unchanged baseline) ----
    ygemm_mfma<384><<<dim3(16, NDT), 256, 0, stream>>>(A2, Bt2, Ybuf, bias2, h2);
    contract_edges<<<E_TOT / 8, 256, 0, stream>>>(Ybuf, eattr, src1, dst1, h2);
    bn_stats<<<64, 256, 0, stream>>>(h2, 2048, stats + 256, stats + 384);
    fused_pool<<<NB, 256, 0, stream>>>(h2, stats + 256, stats + 384, 2048.0f,
                                       gamma2, beta2, pw2, 64, 32,
                                       src1, dst1, src2, dst2, A3);

    // ---- Stage 3 (unchanged baseline) ----
    ygemm_mfma<384><<<dim3(8, NDT), 256, 0, stream>>>(A3, Bt3, Ybuf, bias3, h3);
    contract_edges<<<E_TOT / 8, 256, 0, stream>>>(Ybuf, eattr, src2, dst2, h3);
    bn_stats<<<64, 256, 0, stream>>>(h3, 1024, stats + 512, stats + 640);
    fused_pool_final<<<NB, 256, 0, stream>>>(h3, stats + 512, stats + 640, 1024.0f,
                                             gamma3, beta3, pw3,
                                             lin1_w, lin1_b, lin2_w, lin2_b,
                                             (float*)d_out);
}

// Round 4
// 312.937 us; speedup vs baseline: 1.6941x; 1.3927x over previous
//
#include <hip/hip_runtime.h>

// Problem constants
#define E_TOT 8192
#define NB    32
#define H     128
#define EPG   256          // edges per graph (contiguous slots)
#define NDT   34           // 32 edge-attr dims + 1 bias row + 1 root block
#define YD    33           // Y keeps only d<33 (root fused into h)
#define YCOLS (YD * H)     // 4224

// Stage-1 T-GEMM geometry: K = 33*64 (msg) + 64 (root) = 2176
#define KH1   2176
#define TROW1 (2 * KH1)    // [Th | Tl] per row = 4352 shorts
#define KSPLIT1 12         // hgemm1 k-split (204 k-steps = 12 x 17)

typedef __attribute__((ext_vector_type(8))) short bf16x8;
typedef __attribute__((ext_vector_type(4))) float f32x4;

__device__ __forceinline__ unsigned short bf16_rne(float f) {
    unsigned int u = __float_as_uint(f);
    unsigned int r = (u + 0x7FFFu + ((u >> 16) & 1u)) >> 16;
    return (unsigned short)r;
}
__device__ __forceinline__ float bf16_to_f32(unsigned short h) {
    return __uint_as_float(((unsigned int)h) << 16);
}

__device__ __forceinline__ void gload_lds16(const void* g, void* l) {
    __builtin_amdgcn_global_load_lds(
        (const __attribute__((address_space(1))) unsigned int*)g,
        (__attribute__((address_space(3))) unsigned int*)l, 16, 0, 0);
}

// ---------------------------------------------------------------------------
// build_Bt1n: Bt[o, k'] for the stage-1 T-GEMM, k' = [Wh(2176) | Wl(2176)].
// ---------------------------------------------------------------------------
__global__ __launch_bounds__(256)
void build_Bt1n(const float* __restrict__ nnw, const float* __restrict__ nnb,
                const float* __restrict__ root, unsigned short* __restrict__ Bt)
{
    const int d = blockIdx.x;                       // 0..33
    const float* __restrict__ W =
        (d < 32) ? (nnw + (size_t)d * 8192) : ((d == 32) ? nnb : root);
    const int kbase = d * 64;                       // d=33 -> 2112 (root)

    __shared__ unsigned short LHI[128][72];         // pad 72: 16B-aligned rows
    __shared__ unsigned short LLO[128][72];

    for (int idx = threadIdx.x; idx < 64 * 128; idx += 256) {
        const int ii = idx >> 7, o = idx & 127;
        const float val = W[ii * 128 + o];
        const unsigned short h = bf16_rne(val);
        LHI[o][ii] = h;
        LLO[o][ii] = bf16_rne(val - bf16_to_f32(h));
    }
    __syncthreads();

    const int o    = threadIdx.x & 127;
    const int half = threadIdx.x >> 7;              // 0: hi, 1: lo
    const uint4* s4 = (const uint4*)(half ? &LLO[o][0] : &LHI[o][0]);
    uint4* d4 = (uint4*)(Bt + (size_t)o * TROW1 + (half ? KH1 : 0) + kbase);
    #pragma unroll
    for (int q = 0; q < 8; ++q) d4[q] = s4[q];      // 64 shorts = 128 B
}

// ---------------------------------------------------------------------------
// t1_build (bucketed): grid (32 graphs, 8 chunks of 16 rows), 256 threads.
// Counting-sort edges into per-row LDS buckets, then wave-per-row processes
// only its ~2 edges. T[u] = [Th | Tl]: Th[d*64+i] = sum_{e:dst=u} ea[e,d]*
// x[src,i] (d=32: coef 1), Th[2112+i] = x[u,i]. Exact f32 agg, hi/lo split.
// ---------------------------------------------------------------------------
__global__ __launch_bounds__(256)
void t1_build(const float* __restrict__ x, const float* __restrict__ ea,
              const int* __restrict__ esrc, const int* __restrict__ edst,
              unsigned short* __restrict__ T)
{
    const int g    = blockIdx.x;
    const int base = blockIdx.y * 16;    // 16-row chunk
    const int tid  = threadIdx.x;
    const int wv   = tid >> 6;
    const int ln   = tid & 63;           // input-feature i

    __shared__ float xL[128][64];        // 32 KB
    __shared__ float eaL[256][32];       // 32 KB
    __shared__ short srcL[256];
    __shared__ short lists[16][256];     // 8 KB, provably sufficient capacity
    __shared__ int   cnt[16];

    if (tid < 16) cnt[tid] = 0;
    for (int idx = tid; idx < 128 * 64; idx += 256)
        xL[idx >> 6][idx & 63] = x[(size_t)g * 8192 + idx];
    for (int idx = tid; idx < 256 * 32; idx += 256)
        eaL[idx >> 5][idx & 31] = ea[(size_t)g * 8192 + idx];
    __syncthreads();                     // cnt zeroed before bucketing

    {
        const int e = tid;               // 256 threads = 256 edges (all valid)
        srcL[e] = (short)(esrc[g * EPG + e] - g * 128);
        const int r = (edst[g * EPG + e] - g * 128) - base;
        if (r >= 0 && r < 16) {
            const int pos = atomicAdd(&cnt[r], 1);
            lists[r][pos] = (short)e;
        }
    }
    __syncthreads();

    #pragma unroll
    for (int j = 0; j < 4; ++j) {
        const int r = wv * 4 + j;
        const int u = base + r;
        float acc[33];
        #pragma unroll
        for (int d = 0; d < 33; ++d) acc[d] = 0.f;

        const int n = cnt[r];
        for (int t = 0; t < n; ++t) {
            const int e = lists[r][t];
            const float xv = xL[srcL[e]][ln];
            #pragma unroll
            for (int d = 0; d < 32; ++d) acc[d] += eaL[e][d] * xv;
            acc[32] += xv;               // bias slot, coefficient 1
        }

        unsigned short* row = T + (size_t)(g * 128 + u) * TROW1;
        #pragma unroll
        for (int d = 0; d < 33; ++d) {
            const unsigned short hb = bf16_rne(acc[d]);
            row[d * 64 + ln] = hb;
            row[KH1 + d * 64 + ln] = bf16_rne(acc[d] - bf16_to_f32(hb));
        }
        const float xv = xL[u][ln];      // root section
        const unsigned short hb = bf16_rne(xv);
        row[2112 + ln] = hb;
        row[KH1 + 2112 + ln] = bf16_rne(xv - bf16_to_f32(hb));
    }
}

// ---------------------------------------------------------------------------
// hgemm1: h1-partials = T1' @ Bt1'^T.  204 k-steps in 3 sections
// (s0: Th*Wh, s1: Th*Wl, s2: Tl*Wh), k-split 12 x 17 steps.
// Grid (32, 12); block c writes its own partial slice (streaming, no atomics);
// c==0 adds bias. bn_reduce1 sums the 12 slices.
// ---------------------------------------------------------------------------
__global__ __launch_bounds__(256)
void hgemm1(const unsigned short* __restrict__ A,    // T1 [4096][4352]
            const unsigned short* __restrict__ Bt,   // [128][4352]
            const float* __restrict__ bias,
            float* __restrict__ hpart)               // [12][4096][128]
{
    __shared__ unsigned short Alds[128 * 32];
    __shared__ unsigned short Blds[128 * 32];

    const int lane = threadIdx.x & 63;
    const int w    = threadIdx.x >> 6;
    const int wm = w >> 1, wn = w & 1;
    const int v0 = blockIdx.x * 128;
    const int c  = blockIdx.y;                       // 0..11

    f32x4 acc[4][4];
    #pragma unroll
    for (int i = 0; i < 4; ++i)
        #pragma unroll
        for (int j = 0; j < 4; ++j)
            acc[i][j] = (f32x4)(0.0f);

    const int arow = lane >> 2;
    const int acol = (lane & 3) * 8;
    const int koff = (lane >> 4) * 8;
    const int mrow = lane & 15;

    for (int t = c * 17; t < c * 17 + 17; ++t) {
        const int s  = t / 68;                       // section 0,1,2
        const int ko = (t - s * 68) * 32;
        const int aoff = (s == 2 ? KH1 : 0) + ko;    // s2 reads Tl
        const int boff = (s == 1 ? KH1 : 0) + ko;    // s1 reads Wl

        __syncthreads();
        #pragma unroll
        for (int tt = 0; tt < 2; ++tt) {
            const int cc = w * 2 + tt;
            const int r = cc * 16 + arow;
            gload_lds16(A  + (size_t)(v0 + r) * TROW1 + aoff + acol, &Alds[cc * 512]);
            gload_lds16(Bt + (size_t)r * TROW1 + boff + acol, &Blds[cc * 512]);
        }
        __syncthreads();

        bf16x8 a[4], b[4];
        #pragma unroll
        for (int f = 0; f < 4; ++f) {
            a[f] = *(const bf16x8*)&Alds[(wm * 64 + f * 16 + mrow) * 32 + koff];
            b[f] = *(const bf16x8*)&Blds[(wn * 64 + f * 16 + mrow) * 32 + koff];
        }
        #pragma unroll
        for (int fm = 0; fm < 4; ++fm)
            #pragma unroll
            for (int fn = 0; fn < 4; ++fn)
                acc[fm][fn] = __builtin_amdgcn_mfma_f32_16x16x32_bf16(
                    a[fm], b[fn], acc[fm][fn], 0, 0, 0);
    }

    float* out = hpart + (size_t)c * (4096 * 128);
    const int crow = (lane >> 4) * 4;
    const int ccol = lane & 15;
    #pragma unroll
    for (int fm = 0; fm < 4; ++fm) {
        const int gr = v0 + wm * 64 + fm * 16 + crow;
        #pragma unroll
        for (int fn = 0; fn < 4; ++fn) {
            const int col = wn * 64 + fn * 16 + ccol;
            const float bv = (c == 0) ? bias[col] : 0.f;
            #pragma unroll
            for (int r = 0; r < 4; ++r)
                out[(size_t)(gr + r) * H + col] = acc[fm][fn][r] + bv;
        }
    }
}

// ---------------------------------------------------------------------------
// bn_reduce1: h1 = sum of 12 hgemm1 partials; BN stats in the same pass.
// ---------------------------------------------------------------------------
__global__ __launch_bounds__(256)
void bn_reduce1(const float* __restrict__ hpart, float* __restrict__ h1,
                float* __restrict__ gsum, float* __restrict__ gsumsq)
{
    const int tid   = threadIdx.x;
    const int col   = tid & 127;
    const int rhalf = tid >> 7;
    float s = 0.f, sq = 0.f;
    for (int r = blockIdx.x * 2 + rhalf; r < 4096; r += gridDim.x * 2) {
        float v = 0.f;
        #pragma unroll
        for (int c = 0; c < KSPLIT1; ++c)
            v += hpart[(size_t)c * (4096 * 128) + (size_t)r * H + col];
        h1[(size_t)r * H + col] = v;
        s += v; sq += v * v;
    }
    __shared__ float sh[256];
    sh[tid] = s;  __syncthreads();
    if (rhalf == 0) s += sh[tid + 128];
    __syncthreads();
    sh[tid] = sq; __syncthreads();
    if (rhalf == 0) {
        sq += sh[tid + 128];
        atomicAdd(&gsum[col], s);
        atomicAdd(&gsumsq[col], sq);
    }
}

// ---------------------------------------------------------------------------
// build_Bt (stages 2,3 — unchanged baseline)
// ---------------------------------------------------------------------------
template<int CIN>
__global__ __launch_bounds__(256)
void build_Bt(const float* __restrict__ nnw, const float* __restrict__ nnb,
              const float* __restrict__ root, unsigned short* __restrict__ Bt)
{
    const int d  = blockIdx.x;
    const int i0 = blockIdx.y * 32;
    const float* __restrict__ W =
        (d < 32) ? (nnw + (size_t)d * CIN * 128) : ((d == 32) ? nnb : root);

    __shared__ unsigned short LHI[128][40];
    __shared__ unsigned short LLO[128][40];

    for (int idx = threadIdx.x; idx < 32 * 128; idx += 256) {
        const int ii = idx >> 7, o = idx & 127;
        const float val = W[(size_t)(i0 + ii) * 128 + o];
        const unsigned short h = bf16_rne(val);
        const unsigned short l = bf16_rne(val - bf16_to_f32(h));
        LHI[o][ii] = h; LLO[o][ii] = l;
    }
    __syncthreads();

    const int o    = threadIdx.x & 127;
    const int half = threadIdx.x >> 7;
    unsigned short* dst = Bt + (size_t)(d * 128 + o) * (3 * CIN);
    const uint4* hs = (const uint4*)&LHI[o][0];
    const uint4* ls = (const uint4*)&LLO[o][0];
    if (half == 0) {
        uint4* p = (uint4*)(dst + i0);
        p[0] = hs[0]; p[1] = hs[1]; p[2] = hs[2]; p[3] = hs[3];
        uint4* q = (uint4*)(dst + 2 * CIN + i0);
        q[0] = ls[0]; q[1] = ls[1]; q[2] = ls[2]; q[3] = ls[3];
    } else {
        uint4* p = (uint4*)(dst + CIN + i0);
        p[0] = hs[0]; p[1] = hs[1]; p[2] = hs[2]; p[3] = hs[3];
    }
}

// ---------------------------------------------------------------------------
// ygemm_mfma (stages 2,3 — unchanged baseline)
// ---------------------------------------------------------------------------
template<int K3>
__global__ __launch_bounds__(256)
void ygemm_mfma(const unsigned short* __restrict__ A,
                const unsigned short* __restrict__ Bt,
                float* __restrict__ Y,
                const float* __restrict__ bias,
                float* __restrict__ h)
{
    __shared__ unsigned short Alds[128 * 32];
    __shared__ unsigned short Blds[128 * 32];

    const int lane = threadIdx.x & 63;
    const int w    = threadIdx.x >> 6;
    const int wm = w >> 1, wn = w & 1;
    const int v0 = blockIdx.x * 128;
    const int n0 = blockIdx.y * 128;

    f32x4 acc[4][4];
    #pragma unroll
    for (int i = 0; i < 4; ++i)
        #pragma unroll
        for (int j = 0; j < 4; ++j)
            acc[i][j] = (f32x4)(0.0f);

    const int arow = lane >> 2;
    const int acol = (lane & 3) * 8;
    const int koff = (lane >> 4) * 8;
    const int mrow = lane & 15;

    for (int k0 = 0; k0 < K3; k0 += 32) {
        __syncthreads();
        #pragma unroll
        for (int t = 0; t < 2; ++t) {
            const int c = w * 2 + t;
            const int r = c * 16 + arow;
            gload_lds16(A  + (size_t)(v0 + r) * K3 + k0 + acol, &Alds[c * 512]);
            gload_lds16(Bt + (size_t)(n0 + r) * K3 + k0 + acol, &Blds[c * 512]);
        }
        __syncthreads();

        bf16x8 a[4], b[4];
        #pragma unroll
        for (int f = 0; f < 4; ++f) {
            a[f] = *(const bf16x8*)&Alds[(wm * 64 + f * 16 + mrow) * 32 + koff];
            b[f] = *(const bf16x8*)&Blds[(wn * 64 + f * 16 + mrow) * 32 + koff];
        }
        #pragma unroll
        for (int fm = 0; fm < 4; ++fm)
            #pragma unroll
            for (int fn = 0; fn < 4; ++fn)
                acc[fm][fn] = __builtin_amdgcn_mfma_f32_16x16x32_bf16(
                    a[fm], b[fn], acc[fm][fn], 0, 0, 0);
    }

    const int crow = (lane >> 4) * 4;
    const int ccol = lane & 15;
    const bool is_root = (blockIdx.y == YD);
    #pragma unroll
    for (int fm = 0; fm < 4; ++fm) {
        const int gr = v0 + wm * 64 + fm * 16 + crow;
        #pragma unroll
        for (int fn = 0; fn < 4; ++fn) {
            const int col = wn * 64 + fn * 16 + ccol;   // 0..127 within d-block
            if (is_root) {
                const float bv = bias[col];
                #pragma unroll
                for (int r = 0; r < 4; ++r)
                    h[(size_t)(gr + r) * H + col] = acc[fm][fn][r] + bv;
            } else {
                const size_t gc = (size_t)blockIdx.y * H + col;
                #pragma unroll
                for (int r = 0; r < 4; ++r)
                    Y[(size_t)(gr + r) * YCOLS + gc] = acc[fm][fn][r];
            }
        }
    }
}

// ---------------------------------------------------------------------------
// contract_edges (stages 2,3 — unchanged baseline)
// ---------------------------------------------------------------------------
__global__ __launch_bounds__(256)
void contract_edges(const float* __restrict__ Y,
                    const float* __restrict__ ea,
                    const int*   __restrict__ esrc,
                    const int*   __restrict__ edst,
                    float*       __restrict__ agg)
{
    const int grp = threadIdx.x >> 5;          // 8 groups per block
    const int l5  = threadIdx.x & 31;
    const int e   = blockIdx.x * 8 + grp;
    const int s   = esrc[e];
    if (s < 0) return;

    const float* yb  = Y + (size_t)s * YCOLS + l5 * 4;
    const float* ear = ea + (size_t)e * 32;

    float4 acc = *reinterpret_cast<const float4*>(yb + 32 * H);   // bias row, coef 1
    #pragma unroll 8
    for (int dd = 0; dd < 32; ++dd) {
        const float c = ear[dd];
        const float4 y = *reinterpret_cast<const float4*>(yb + dd * H);
        acc.x += c * y.x; acc.y += c * y.y; acc.z += c * y.z; acc.w += c * y.w;
    }
    float* out = agg + (size_t)edst[e] * H + l5 * 4;
    atomicAdd(out + 0, acc.x);
    atomicAdd(out + 1, acc.y);
    atomicAdd(out + 2, acc.z);
    atomicAdd(out + 3, acc.w);
}

// Column sums / sumsq over n rows of raw h, atomically accumulated.
__global__ __launch_bounds__(256)
void bn_stats(const float* __restrict__ h, int n,
              float* __restrict__ gsum, float* __restrict__ gsumsq)
{
    const int tid   = threadIdx.x;
    const int col   = tid & 127;
    const int rhalf = tid >> 7;
    float s = 0.f, sq = 0.f;
    for (int r = blockIdx.x * 2 + rhalf; r < n; r += gridDim.x * 2) {
        float v = h[(size_t)r * H + col];
        s += v; sq += v * v;
    }
    __shared__ float sh[256];
    sh[tid] = s;  __syncthreads();
    if (rhalf == 0) s += sh[tid + 128];
    __syncthreads();
    sh[tid] = sq; __syncthreads();
    if (rhalf == 0) {
        sq += sh[tid + 128];
        atomicAdd(&gsum[col], s);
        atomicAdd(&gsumsq[col], sq);
    }
}

// ---------------------------------------------------------------------------
// fused_pool: BN + ReLU + score + top-k + next-stage A' emission + edge remap.
// (unchanged baseline)
// ---------------------------------------------------------------------------
__global__ __launch_bounds__(256)
void fused_pool(const float* __restrict__ h,
                const float* __restrict__ gsum, const float* __restrict__ gsumsq,
                float n_f,
                const float* __restrict__ gamma, const float* __restrict__ beta,
                const float* __restrict__ pw,
                int npg, int k,
                const int* __restrict__ esrc_in, const int* __restrict__ edst_in,
                int* __restrict__ esrc_out, int* __restrict__ edst_out,
                unsigned short* __restrict__ Aout)   // [NB*k, 384]
{
    const int g   = blockIdx.x;
    const int tid = threadIdx.x;
    const int wv  = tid >> 6;
    const int ln  = tid & 63;

    __shared__ float muL[128], rsL[128], gmL[128], btL[128], pwL[128];
    __shared__ float scoreL[128], red[128];
    __shared__ int   mapL[128];
    __shared__ float sinv;

    if (tid < 128) {
        const float mu  = gsum[tid] / n_f;
        const float var = gsumsq[tid] / n_f - mu * mu;
        muL[tid] = mu;
        rsL[tid] = rsqrtf(var + 1e-5f);
        gmL[tid] = gamma[tid];
        btL[tid] = beta[tid];
        const float p = pw[tid];
        pwL[tid] = p;
        red[tid] = p * p;
    }
    __syncthreads();
    for (int off = 64; off > 0; off >>= 1) {
        if (tid < off) red[tid] += red[tid + off];
        __syncthreads();
    }
    if (tid == 0) sinv = rsqrtf(red[0]);
    __syncthreads();

    for (int r = wv; r < npg; r += 4) {
        const float* hr = h + (size_t)(g * npg + r) * H;
        float p = 0.f;
        #pragma unroll
        for (int half = 0; half < 2; ++half) {
            const int c = ln + half * 64;
            const float y = fmaxf(gmL[c] * (hr[c] - muL[c]) * rsL[c] + btL[c], 0.f);
            p += y * pwL[c];
        }
        #pragma unroll
        for (int off = 32; off > 0; off >>= 1)
            p += __shfl_down(p, off, 64);
        if (ln == 0) scoreL[r] = tanhf(p * sinv);
    }
    __syncthreads();

    if (tid < npg) {
        const float si = scoreL[tid];
        int cnt = 0;
        for (int j = 0; j < npg; ++j) {
            const float sj = scoreL[j];
            cnt += (sj > si) || (sj == si && j < tid);
        }
        mapL[tid] = (cnt < k) ? cnt : -1;
    }
    __syncthreads();

    for (int r = wv; r < npg; r += 4) {
        const int nr = mapL[r];
        if (nr < 0) continue;
        const float sc = scoreL[r];
        const float* hr = h + (size_t)(g * npg + r) * H;
        unsigned short* arow = Aout + (size_t)(g * k + nr) * 384;
        #pragma unroll
        for (int half = 0; half < 2; ++half) {
            const int c = ln + half * 64;
            const float y = fmaxf(gmL[c] * (hr[c] - muL[c]) * rsL[c] + btL[c], 0.f) * sc;
            const unsigned short hb = bf16_rne(y);
            const unsigned short lb = bf16_rne(y - bf16_to_f32(hb));
            arow[c] = hb; arow[128 + c] = hb; arow[256 + c] = lb;
        }
    }

    {
        const int e = g * EPG + tid;   // tid in [0,256)
        const int s = esrc_in[e];
        int ns = -1, nd = -1;
        if (s >= 0) {
            const int ms = mapL[s - g * npg];
            const int md = mapL[edst_in[e] - g * npg];
            if (ms >= 0 && md >= 0) { ns = g * k + ms; nd = g * k + md; }
        }
        esrc_out[e] = ns; edst_out[e] = nd;
    }
}

// ---------------------------------------------------------------------------
// fused_pool_final: stage-3 pool (npg=32,k=16) + mean-pool + MLP + sigmoid.
// (unchanged baseline)
// ---------------------------------------------------------------------------
__global__ __launch_bounds__(256)
void fused_pool_final(const float* __restrict__ h,
                      const float* __restrict__ gsum, const float* __restrict__ gsumsq,
                      float n_f,
                      const float* __restrict__ gamma, const float* __restrict__ beta,
                      const float* __restrict__ pw,
                      const float* __restrict__ lin1_w, const float* __restrict__ lin1_b,
                      const float* __restrict__ lin2_w, const float* __restrict__ lin2_b,
                      float* __restrict__ out)
{
    const int g   = blockIdx.x;
    const int tid = threadIdx.x;
    const int wv  = tid >> 6;
    const int ln  = tid & 63;
    const int npg = 32, k = 16;

    __shared__ float muL[128], rsL[128], gmL[128], btL[128], pwL[128];
    __shared__ float scoreL[32], red[128], gmean[128], h1c[64];
    __shared__ int   mapL[32];
    __shared__ float sinv;

    if (tid < 128) {
        const float mu  = gsum[tid] / n_f;
        const float var = gsumsq[tid] / n_f - mu * mu;
        muL[tid] = mu;
        rsL[tid] = rsqrtf(var + 1e-5f);
        gmL[tid] = gamma[tid];
        btL[tid] = beta[tid];
        const float p = pw[tid];
        pwL[tid] = p;
        red[tid] = p * p;
    }
    __syncthreads();
    for (int off = 64; off > 0; off >>= 1) {
        if (tid < off) red[tid] += red[tid + off];
        __syncthreads();
    }
    if (tid == 0) sinv = rsqrtf(red[0]);
    __syncthreads();

    for (int r = wv; r < npg; r += 4) {
        const float* hr = h + (size_t)(g * npg + r) * H;
        float p = 0.f;
        #pragma unroll
        for (int half = 0; half < 2; ++half) {
            const int c = ln + half * 64;
            const float y = fmaxf(gmL[c] * (hr[c] - muL[c]) * rsL[c] + btL[c], 0.f);
            p += y * pwL[c];
        }
        #pragma unroll
        for (int off = 32; off > 0; off >>= 1)
            p += __shfl_down(p, off, 64);
        if (ln == 0) scoreL[r] = tanhf(p * sinv);
    }
    __syncthreads();

    if (tid < npg) {
        const float si = scoreL[tid];
        int cnt = 0;
        for (int j = 0; j < npg; ++j) {
            const float sj = scoreL[j];
            cnt += (sj > si) || (sj == si && j < tid);
        }
        mapL[tid] = (cnt < k) ? cnt : -1;
    }
    __syncthreads();

    if (tid < 128) {
        float acc = 0.f;
        for (int r = 0; r < npg; ++r) {
            if (mapL[r] < 0) continue;
            const float hv = h[(size_t)(g * npg + r) * H + tid];
            const float y  = fmaxf(gmL[tid] * (hv - muL[tid]) * rsL[tid] + btL[tid], 0.f);
            acc += y * scoreL[r];
        }
        gmean[tid] = acc * (1.0f / 16.0f);
    }
    __syncthreads();

    if (tid < 64) {
        float acc = lin1_b[tid];
        for (int o = 0; o < 128; ++o) acc += gmean[o] * lin1_w[o * 64 + tid];
        h1c[tid] = fmaxf(acc, 0.f);
    }
    __syncthreads();
    if (tid == 0) {
        float z = lin2_b[0];
        for (int j = 0; j < 64; ++j) z += h1c[j] * lin2_w[j];
        out[g] = 1.0f / (1.0f + expf(-z));
    }
}

extern "C" void kernel_launch(void* const* d_in, const int* in_sizes, int n_in,
                              void* d_out, int out_size, void* d_ws, size_t ws_size,
                              hipStream_t stream)
{
    const float* x        = (const float*)d_in[0];
    const int*   ei       = (const int*)  d_in[1];
    const float* eattr    = (const float*)d_in[2];
    const float* nn1_w    = (const float*)d_in[4];
    const float* nn1_b    = (const float*)d_in[5];
    const float* root1    = (const float*)d_in[6];
    const float* bias1    = (const float*)d_in[7];
    const float* nn2_w    = (const float*)d_in[8];
    const float* nn2_b    = (const float*)d_in[9];
    const float* root2    = (const float*)d_in[10];
    const float* bias2    = (const float*)d_in[11];
    const float* nn3_w    = (const float*)d_in[12];
    const float* nn3_b    = (const float*)d_in[13];
    const float* root3    = (const float*)d_in[14];
    const float* bias3    = (const float*)d_in[15];
    const float* gamma1   = (const float*)d_in[16];
    const float* beta1    = (const float*)d_in[17];
    const float* gamma2   = (const float*)d_in[18];
    const float* beta2    = (const float*)d_in[19];
    const float* gamma3   = (const float*)d_in[20];
    const float* beta3    = (const float*)d_in[21];
    const float* pw1      = (const float*)d_in[22];
    const float* pw2      = (const float*)d_in[23];
    const float* pw3      = (const float*)d_in[24];
    const float* lin1_w   = (const float*)d_in[25];
    const float* lin1_b   = (const float*)d_in[26];
    const float* lin2_w   = (const float*)d_in[27];
    const float* lin2_b   = (const float*)d_in[28];

    const int* ei_src = ei;
    const int* ei_dst = ei + E_TOT;

    char* wp = (char*)d_ws;
    auto alloc = [&](size_t bytes) { char* p = wp; wp += (bytes + 255) & ~(size_t)255; return p; };
    float* h1   = (float*)alloc(4096 * 128 * 4);
    float* h2   = (float*)alloc(2048 * 128 * 4);
    float* h3   = (float*)alloc(1024 * 128 * 4);
    int*   src1 = (int*)alloc(E_TOT * 4);
    int*   dst1 = (int*)alloc(E_TOT * 4);
    int*   src2 = (int*)alloc(E_TOT * 4);
    int*   dst2 = (int*)alloc(E_TOT * 4);
    float* stats = (float*)alloc(6 * 128 * 4);
    unsigned short* A2   = (unsigned short*)alloc((size_t)2048 * 384 * 2);
    unsigned short* A3   = (unsigned short*)alloc((size_t)1024 * 384 * 2);
    unsigned short* Bt1n = (unsigned short*)alloc((size_t)128 * TROW1 * 2);
    unsigned short* Bt2  = (unsigned short*)alloc((size_t)4352 * 384 * 2);
    unsigned short* Bt3  = (unsigned short*)alloc((size_t)4352 * 384 * 2);
    unsigned short* T1   = (unsigned short*)alloc((size_t)4096 * TROW1 * 2);   // 35.7 MB
    float* hpart = (float*)alloc((size_t)KSPLIT1 * 4096 * 128 * 4);            // 25 MB
    float* Ybuf = (float*)alloc((size_t)2048 * YCOLS * 4);   // stages 2,3 only

    hipMemsetAsync(stats, 0, 6 * 128 * sizeof(float), stream);

    // Weight preprocessing
    build_Bt1n<<<NDT, 256, 0, stream>>>(nn1_w, nn1_b, root1, Bt1n);
    build_Bt<128><<<dim3(NDT, 4), 256, 0, stream>>>(nn2_w, nn2_b, root2, Bt2);
    build_Bt<128><<<dim3(NDT, 4), 256, 0, stream>>>(nn3_w, nn3_b, root3, Bt3);

    // ---- Stage 1: aggregate-first (bucketed T1) + k-split GEMM + fused reduce ----
    t1_build<<<dim3(NB, 8), 256, 0, stream>>>(x, eattr, ei_src, ei_dst, T1);
    hgemm1<<<dim3(32, KSPLIT1), 256, 0, stream>>>(T1, Bt1n, bias1, hpart);
    bn_reduce1<<<64, 256, 0, stream>>>(hpart, h1, stats, stats + 128);
    fused_pool<<<NB, 256, 0, stream>>>(h1, stats, stats + 128, 4096.0f,
                                       gamma1, beta1, pw1, 128, 64,
                                       ei_src, ei_dst, src1, dst1, A2);

    // ---- Stage 2 (unchanged baseline) ----
    ygemm_mfma<384><<<dim3(16, NDT), 256, 0, stream>>>(A2, Bt2, Ybuf, bias2, h2);
    contract_edges<<<E_TOT / 8, 256, 0, stream>>>(Ybuf, eattr, src1, dst1, h2);
    bn_stats<<<64, 256, 0, stream>>>(h2, 2048, stats + 256, stats + 384);
    fused_pool<<<NB, 256, 0, stream>>>(h2, stats + 256, stats + 384, 2048.0f,
                                       gamma2, beta2, pw2, 64, 32,
                                       src1, dst1, src2, dst2, A3);

    // ---- Stage 3 (unchanged baseline) ----
    ygemm_mfma<384><<<dim3(8, NDT), 256, 0, stream>>>(A3, Bt3, Ybuf, bias3, h3);
    contract_edges<<<E_TOT / 8, 256, 0, stream>>>(Ybuf, eattr, src2, dst2, h3);
    bn_stats<<<64, 256, 0, stream>>>(h3, 1024, stats + 512, stats + 640);
    fused_pool_final<<<NB, 256, 0, stream>>>(h3, stats + 512, stats + 640, 1024.0f,
                                             gamma3, beta3, pw3,
                                             lin1_w, lin1_b, lin2_w, lin2_b,
                                             (float*)d_out);
}

// Round 5
// 291.619 us; speedup vs baseline: 1.8180x; 1.0731x over previous
//
#include <hip/hip_runtime.h>

// Problem constants
#define E_TOT 8192
#define NB    32
#define H     128
#define EPG   256          // edges per graph (contiguous slots)
#define NDT   34           // 32 edge-attr dims + 1 bias row + 1 root block
#define YD    33           // Y keeps only d<33 (root fused into h)
#define YCOLS (YD * H)     // 4224

// Stage-1 T-GEMM geometry: K = 33*64 (msg) + 64 (root) = 2176
#define KH1   2176
#define TROW1 (2 * KH1)    // [Th | Tl] per row = 4352 shorts
#define KSPLIT1 12         // hgemm1 k-split (204 k-steps = 12 x 17)

typedef __attribute__((ext_vector_type(8))) short bf16x8;
typedef __attribute__((ext_vector_type(4))) float f32x4;

__device__ __forceinline__ unsigned short bf16_rne(float f) {
    unsigned int u = __float_as_uint(f);
    unsigned int r = (u + 0x7FFFu + ((u >> 16) & 1u)) >> 16;
    return (unsigned short)r;
}
__device__ __forceinline__ float bf16_to_f32(unsigned short h) {
    return __uint_as_float(((unsigned int)h) << 16);
}

__device__ __forceinline__ void gload_lds16(const void* g, void* l) {
    __builtin_amdgcn_global_load_lds(
        (const __attribute__((address_space(1))) unsigned int*)g,
        (__attribute__((address_space(3))) unsigned int*)l, 16, 0, 0);
}

// ---------------------------------------------------------------------------
// prep_all: ONE kernel for all input-side preprocessing (saves 4 dispatch
// boundaries @ ~11 us each). Units by blockIdx.x:
//   [0,34)    : Bt1n unit (stage-1 T-GEMM weights, [Wh|Wl] layout)
//   [34,306)  : baseline build_Bt<128> units for stages 2,3 (verbatim,
//               bug-compatible [HI|HI|LO] layout — BN absorbs the affine)
//   [306,562) : t1_build unit (bucketed T1 aggregation, verbatim from R4)
// Block 0 additionally zeroes the 768-float stats buffer.
// ---------------------------------------------------------------------------
union PrepSMem {
    struct { unsigned short HI[128][72]; unsigned short LO[128][72]; } b1;  // 36,864 B
    struct { unsigned short HI[128][40]; unsigned short LO[128][40]; } bt;  // 20,480 B
    struct { float xL[128][64]; float eaL[256][32]; short srcL[256];
             short lists[16][256]; int cnt[16]; } t1;                        // 74,304 B
};

__global__ __launch_bounds__(256)
void prep_all(const float* __restrict__ x, const float* __restrict__ ea,
              const int* __restrict__ esrc, const int* __restrict__ edst,
              const float* __restrict__ nn1w, const float* __restrict__ nn1b,
              const float* __restrict__ root1,
              const float* __restrict__ nn2w, const float* __restrict__ nn2b,
              const float* __restrict__ root2,
              const float* __restrict__ nn3w, const float* __restrict__ nn3b,
              const float* __restrict__ root3,
              unsigned short* __restrict__ Bt1, unsigned short* __restrict__ Bt2,
              unsigned short* __restrict__ Bt3, unsigned short* __restrict__ T1,
              float* __restrict__ stats)
{
    __shared__ PrepSMem sm;
    const int b   = blockIdx.x;
    const int tid = threadIdx.x;

    if (b < 34) {
        // ---- Bt1n unit (d = b): correct 3-term split layout [Wh | Wl] ----
        if (b == 0)
            for (int i = tid; i < 768; i += 256) stats[i] = 0.f;
        const int d = b;
        const float* __restrict__ W =
            (d < 32) ? (nn1w + (size_t)d * 8192) : ((d == 32) ? nn1b : root1);
        for (int idx = tid; idx < 64 * 128; idx += 256) {
            const int ii = idx >> 7, o = idx & 127;
            const float v = W[ii * 128 + o];
            const unsigned short h = bf16_rne(v);
            sm.b1.HI[o][ii] = h;
            sm.b1.LO[o][ii] = bf16_rne(v - bf16_to_f32(h));
        }
        __syncthreads();
        const int o = tid & 127, half = tid >> 7;
        const uint4* s4 = (const uint4*)(half ? &sm.b1.LO[o][0] : &sm.b1.HI[o][0]);
        uint4* d4 = (uint4*)(Bt1 + (size_t)o * TROW1 + (half ? KH1 : 0) + d * 64);
        #pragma unroll
        for (int q = 0; q < 8; ++q) d4[q] = s4[q];
    } else if (b < 306) {
        // ---- baseline build_Bt<128> unit (verbatim, stages 2 & 3) ----
        const int unit  = b - 34;
        const int stage = unit / 136;            // 0: stage2, 1: stage3
        const int u2    = unit - stage * 136;
        const int d  = u2 >> 2;
        const int i0 = (u2 & 3) * 32;
        const float* __restrict__ W = (stage == 0)
            ? ((d < 32) ? (nn2w + (size_t)d * 16384) : ((d == 32) ? nn2b : root2))
            : ((d < 32) ? (nn3w + (size_t)d * 16384) : ((d == 32) ? nn3b : root3));
        unsigned short* __restrict__ Bt = (stage == 0) ? Bt2 : Bt3;

        for (int idx = tid; idx < 32 * 128; idx += 256) {
            const int ii = idx >> 7, o = idx & 127;
            const float v = W[(size_t)(i0 + ii) * 128 + o];
            const unsigned short h = bf16_rne(v);
            sm.bt.HI[o][ii] = h;
            sm.bt.LO[o][ii] = bf16_rne(v - bf16_to_f32(h));
        }
        __syncthreads();
        const int o = tid & 127, half = tid >> 7;
        unsigned short* dst = Bt + (size_t)(d * 128 + o) * 384;
        const uint4* hs = (const uint4*)&sm.bt.HI[o][0];
        const uint4* ls = (const uint4*)&sm.bt.LO[o][0];
        if (half == 0) {
            uint4* p = (uint4*)(dst + i0);
            p[0] = hs[0]; p[1] = hs[1]; p[2] = hs[2]; p[3] = hs[3];
            uint4* q = (uint4*)(dst + 256 + i0);
            q[0] = ls[0]; q[1] = ls[1]; q[2] = ls[2]; q[3] = ls[3];
        } else {
            uint4* p = (uint4*)(dst + 128 + i0);
            p[0] = hs[0]; p[1] = hs[1]; p[2] = hs[2]; p[3] = hs[3];
        }
    } else {
        // ---- t1_build unit (verbatim bucketed aggregation from R4) ----
        const int u    = b - 306;
        const int g    = u >> 3;
        const int base = (u & 7) * 16;
        const int wv   = tid >> 6;
        const int ln   = tid & 63;

        if (tid < 16) sm.t1.cnt[tid] = 0;
        for (int idx = tid; idx < 128 * 64; idx += 256)
            sm.t1.xL[idx >> 6][idx & 63] = x[(size_t)g * 8192 + idx];
        for (int idx = tid; idx < 256 * 32; idx += 256)
            sm.t1.eaL[idx >> 5][idx & 31] = ea[(size_t)g * 8192 + idx];
        __syncthreads();

        {
            const int e = tid;               // 256 threads = 256 edges (all valid)
            sm.t1.srcL[e] = (short)(esrc[g * EPG + e] - g * 128);
            const int r = (edst[g * EPG + e] - g * 128) - base;
            if (r >= 0 && r < 16) {
                const int pos = atomicAdd(&sm.t1.cnt[r], 1);
                sm.t1.lists[r][pos] = (short)e;
            }
        }
        __syncthreads();

        #pragma unroll
        for (int j = 0; j < 4; ++j) {
            const int r = wv * 4 + j;
            const int uu = base + r;
            float acc[33];
            #pragma unroll
            for (int d = 0; d < 33; ++d) acc[d] = 0.f;

            const int n = sm.t1.cnt[r];
            for (int t = 0; t < n; ++t) {
                const int e = sm.t1.lists[r][t];
                const float xv = sm.t1.xL[sm.t1.srcL[e]][ln];
                #pragma unroll
                for (int d = 0; d < 32; ++d) acc[d] += sm.t1.eaL[e][d] * xv;
                acc[32] += xv;               // bias slot, coefficient 1
            }

            unsigned short* row = T1 + (size_t)(g * 128 + uu) * TROW1;
            #pragma unroll
            for (int d = 0; d < 33; ++d) {
                const unsigned short hb = bf16_rne(acc[d]);
                row[d * 64 + ln] = hb;
                row[KH1 + d * 64 + ln] = bf16_rne(acc[d] - bf16_to_f32(hb));
            }
            const float xv = sm.t1.xL[uu][ln];   // root section
            const unsigned short hb = bf16_rne(xv);
            row[2112 + ln] = hb;
            row[KH1 + 2112 + ln] = bf16_rne(xv - bf16_to_f32(hb));
        }
    }
}

// ---------------------------------------------------------------------------
// hgemm1: h1-partials = T1' @ Bt1'^T.  204 k-steps in 3 sections
// (s0: Th*Wh, s1: Th*Wl, s2: Tl*Wh), k-split 12 x 17 steps. (verbatim R4)
// ---------------------------------------------------------------------------
__global__ __launch_bounds__(256)
void hgemm1(const unsigned short* __restrict__ A,    // T1 [4096][4352]
            const unsigned short* __restrict__ Bt,   // [128][4352]
            const float* __restrict__ bias,
            float* __restrict__ hpart)               // [12][4096][128]
{
    __shared__ unsigned short Alds[128 * 32];
    __shared__ unsigned short Blds[128 * 32];

    const int lane = threadIdx.x & 63;
    const int w    = threadIdx.x >> 6;
    const int wm = w >> 1, wn = w & 1;
    const int v0 = blockIdx.x * 128;
    const int c  = blockIdx.y;                       // 0..11

    f32x4 acc[4][4];
    #pragma unroll
    for (int i = 0; i < 4; ++i)
        #pragma unroll
        for (int j = 0; j < 4; ++j)
            acc[i][j] = (f32x4)(0.0f);

    const int arow = lane >> 2;
    const int acol = (lane & 3) * 8;
    const int koff = (lane >> 4) * 8;
    const int mrow = lane & 15;

    for (int t = c * 17; t < c * 17 + 17; ++t) {
        const int s  = t / 68;                       // section 0,1,2
        const int ko = (t - s * 68) * 32;
        const int aoff = (s == 2 ? KH1 : 0) + ko;    // s2 reads Tl
        const int boff = (s == 1 ? KH1 : 0) + ko;    // s1 reads Wl

        __syncthreads();
        #pragma unroll
        for (int tt = 0; tt < 2; ++tt) {
            const int cc = w * 2 + tt;
            const int r = cc * 16 + arow;
            gload_lds16(A  + (size_t)(v0 + r) * TROW1 + aoff + acol, &Alds[cc * 512]);
            gload_lds16(Bt + (size_t)r * TROW1 + boff + acol, &Blds[cc * 512]);
        }
        __syncthreads();

        bf16x8 a[4], b[4];
        #pragma unroll
        for (int f = 0; f < 4; ++f) {
            a[f] = *(const bf16x8*)&Alds[(wm * 64 + f * 16 + mrow) * 32 + koff];
            b[f] = *(const bf16x8*)&Blds[(wn * 64 + f * 16 + mrow) * 32 + koff];
        }
        #pragma unroll
        for (int fm = 0; fm < 4; ++fm)
            #pragma unroll
            for (int fn = 0; fn < 4; ++fn)
                acc[fm][fn] = __builtin_amdgcn_mfma_f32_16x16x32_bf16(
                    a[fm], b[fn], acc[fm][fn], 0, 0, 0);
    }

    float* out = hpart + (size_t)c * (4096 * 128);
    const int crow = (lane >> 4) * 4;
    const int ccol = lane & 15;
    #pragma unroll
    for (int fm = 0; fm < 4; ++fm) {
        const int gr = v0 + wm * 64 + fm * 16 + crow;
        #pragma unroll
        for (int fn = 0; fn < 4; ++fn) {
            const int col = wn * 64 + fn * 16 + ccol;
            const float bv = (c == 0) ? bias[col] : 0.f;
            #pragma unroll
            for (int r = 0; r < 4; ++r)
                out[(size_t)(gr + r) * H + col] = acc[fm][fn][r] + bv;
        }
    }
}

// ---------------------------------------------------------------------------
// bn_reduce1: h1 = sum of 12 partials; BN stats same pass. Grid 256 (was 64:
// reading 25 MB from 1/4 of the chip was BW-starved).
// ---------------------------------------------------------------------------
__global__ __launch_bounds__(256)
void bn_reduce1(const float* __restrict__ hpart, float* __restrict__ h1,
                float* __restrict__ gsum, float* __restrict__ gsumsq)
{
    const int tid   = threadIdx.x;
    const int col   = tid & 127;
    const int rhalf = tid >> 7;
    float s = 0.f, sq = 0.f;
    for (int r = blockIdx.x * 2 + rhalf; r < 4096; r += gridDim.x * 2) {
        float v = 0.f;
        #pragma unroll
        for (int c = 0; c < KSPLIT1; ++c)
            v += hpart[(size_t)c * (4096 * 128) + (size_t)r * H + col];
        h1[(size_t)r * H + col] = v;
        s += v; sq += v * v;
    }
    __shared__ float sh[256];
    sh[tid] = s;  __syncthreads();
    if (rhalf == 0) s += sh[tid + 128];
    __syncthreads();
    sh[tid] = sq; __syncthreads();
    if (rhalf == 0) {
        sq += sh[tid + 128];
        atomicAdd(&gsum[col], s);
        atomicAdd(&gsumsq[col], sq);
    }
}

// ---------------------------------------------------------------------------
// ygemm_mfma (stages 2,3 — unchanged baseline)
// ---------------------------------------------------------------------------
template<int K3>
__global__ __launch_bounds__(256)
void ygemm_mfma(const unsigned short* __restrict__ A,
                const unsigned short* __restrict__ Bt,
                float* __restrict__ Y,
                const float* __restrict__ bias,
                float* __restrict__ h)
{
    __shared__ unsigned short Alds[128 * 32];
    __shared__ unsigned short Blds[128 * 32];

    const int lane = threadIdx.x & 63;
    const int w    = threadIdx.x >> 6;
    const int wm = w >> 1, wn = w & 1;
    const int v0 = blockIdx.x * 128;
    const int n0 = blockIdx.y * 128;

    f32x4 acc[4][4];
    #pragma unroll
    for (int i = 0; i < 4; ++i)
        #pragma unroll
        for (int j = 0; j < 4; ++j)
            acc[i][j] = (f32x4)(0.0f);

    const int arow = lane >> 2;
    const int acol = (lane & 3) * 8;
    const int koff = (lane >> 4) * 8;
    const int mrow = lane & 15;

    for (int k0 = 0; k0 < K3; k0 += 32) {
        __syncthreads();
        #pragma unroll
        for (int t = 0; t < 2; ++t) {
            const int c = w * 2 + t;
            const int r = c * 16 + arow;
            gload_lds16(A  + (size_t)(v0 + r) * K3 + k0 + acol, &Alds[c * 512]);
            gload_lds16(Bt + (size_t)(n0 + r) * K3 + k0 + acol, &Blds[c * 512]);
        }
        __syncthreads();

        bf16x8 a[4], b[4];
        #pragma unroll
        for (int f = 0; f < 4; ++f) {
            a[f] = *(const bf16x8*)&Alds[(wm * 64 + f * 16 + mrow) * 32 + koff];
            b[f] = *(const bf16x8*)&Blds[(wn * 64 + f * 16 + mrow) * 32 + koff];
        }
        #pragma unroll
        for (int fm = 0; fm < 4; ++fm)
            #pragma unroll
            for (int fn = 0; fn < 4; ++fn)
                acc[fm][fn] = __builtin_amdgcn_mfma_f32_16x16x32_bf16(
                    a[fm], b[fn], acc[fm][fn], 0, 0, 0);
    }

    const int crow = (lane >> 4) * 4;
    const int ccol = lane & 15;
    const bool is_root = (blockIdx.y == YD);
    #pragma unroll
    for (int fm = 0; fm < 4; ++fm) {
        const int gr = v0 + wm * 64 + fm * 16 + crow;
        #pragma unroll
        for (int fn = 0; fn < 4; ++fn) {
            const int col = wn * 64 + fn * 16 + ccol;   // 0..127 within d-block
            if (is_root) {
                const float bv = bias[col];
                #pragma unroll
                for (int r = 0; r < 4; ++r)
                    h[(size_t)(gr + r) * H + col] = acc[fm][fn][r] + bv;
            } else {
                const size_t gc = (size_t)blockIdx.y * H + col;
                #pragma unroll
                for (int r = 0; r < 4; ++r)
                    Y[(size_t)(gr + r) * YCOLS + gc] = acc[fm][fn][r];
            }
        }
    }
}

// ---------------------------------------------------------------------------
// contract_edges (stages 2,3 — unchanged baseline)
// ---------------------------------------------------------------------------
__global__ __launch_bounds__(256)
void contract_edges(const float* __restrict__ Y,
                    const float* __restrict__ ea,
                    const int*   __restrict__ esrc,
                    const int*   __restrict__ edst,
                    float*       __restrict__ agg)
{
    const int grp = threadIdx.x >> 5;          // 8 groups per block
    const int l5  = threadIdx.x & 31;
    const int e   = blockIdx.x * 8 + grp;
    const int s   = esrc[e];
    if (s < 0) return;

    const float* yb  = Y + (size_t)s * YCOLS + l5 * 4;
    const float* ear = ea + (size_t)e * 32;

    float4 acc = *reinterpret_cast<const float4*>(yb + 32 * H);   // bias row, coef 1
    #pragma unroll 8
    for (int dd = 0; dd < 32; ++dd) {
        const float c = ear[dd];
        const float4 y = *reinterpret_cast<const float4*>(yb + dd * H);
        acc.x += c * y.x; acc.y += c * y.y; acc.z += c * y.z; acc.w += c * y.w;
    }
    float* out = agg + (size_t)edst[e] * H + l5 * 4;
    atomicAdd(out + 0, acc.x);
    atomicAdd(out + 1, acc.y);
    atomicAdd(out + 2, acc.z);
    atomicAdd(out + 3, acc.w);
}

// Column sums / sumsq over n rows of raw h, atomically accumulated.
__global__ __launch_bounds__(256)
void bn_stats(const float* __restrict__ h, int n,
              float* __restrict__ gsum, float* __restrict__ gsumsq)
{
    const int tid   = threadIdx.x;
    const int col   = tid & 127;
    const int rhalf = tid >> 7;
    float s = 0.f, sq = 0.f;
    for (int r = blockIdx.x * 2 + rhalf; r < n; r += gridDim.x * 2) {
        float v = h[(size_t)r * H + col];
        s += v; sq += v * v;
    }
    __shared__ float sh[256];
    sh[tid] = s;  __syncthreads();
    if (rhalf == 0) s += sh[tid + 128];
    __syncthreads();
    sh[tid] = sq; __syncthreads();
    if (rhalf == 0) {
        sq += sh[tid + 128];
        atomicAdd(&gsum[col], s);
        atomicAdd(&gsumsq[col], sq);
    }
}

// ---------------------------------------------------------------------------
// fused_pool: BN + ReLU + score + top-k + next-stage A' emission + edge remap.
// (unchanged baseline)
// ---------------------------------------------------------------------------
__global__ __launch_bounds__(256)
void fused_pool(const float* __restrict__ h,
                const float* __restrict__ gsum, const float* __restrict__ gsumsq,
                float n_f,
                const float* __restrict__ gamma, const float* __restrict__ beta,
                const float* __restrict__ pw,
                int npg, int k,
                const int* __restrict__ esrc_in, const int* __restrict__ edst_in,
                int* __restrict__ esrc_out, int* __restrict__ edst_out,
                unsigned short* __restrict__ Aout)   // [NB*k, 384]
{
    const int g   = blockIdx.x;
    const int tid = threadIdx.x;
    const int wv  = tid >> 6;
    const int ln  = tid & 63;

    __shared__ float muL[128], rsL[128], gmL[128], btL[128], pwL[128];
    __shared__ float scoreL[128], red[128];
    __shared__ int   mapL[128];
    __shared__ float sinv;

    if (tid < 128) {
        const float mu  = gsum[tid] / n_f;
        const float var = gsumsq[tid] / n_f - mu * mu;
        muL[tid] = mu;
        rsL[tid] = rsqrtf(var + 1e-5f);
        gmL[tid] = gamma[tid];
        btL[tid] = beta[tid];
        const float p = pw[tid];
        pwL[tid] = p;
        red[tid] = p * p;
    }
    __syncthreads();
    for (int off = 64; off > 0; off >>= 1) {
        if (tid < off) red[tid] += red[tid + off];
        __syncthreads();
    }
    if (tid == 0) sinv = rsqrtf(red[0]);
    __syncthreads();

    for (int r = wv; r < npg; r += 4) {
        const float* hr = h + (size_t)(g * npg + r) * H;
        float p = 0.f;
        #pragma unroll
        for (int half = 0; half < 2; ++half) {
            const int c = ln + half * 64;
            const float y = fmaxf(gmL[c] * (hr[c] - muL[c]) * rsL[c] + btL[c], 0.f);
            p += y * pwL[c];
        }
        #pragma unroll
        for (int off = 32; off > 0; off >>= 1)
            p += __shfl_down(p, off, 64);
        if (ln == 0) scoreL[r] = tanhf(p * sinv);
    }
    __syncthreads();

    if (tid < npg) {
        const float si = scoreL[tid];
        int cnt = 0;
        for (int j = 0; j < npg; ++j) {
            const float sj = scoreL[j];
            cnt += (sj > si) || (sj == si && j < tid);
        }
        mapL[tid] = (cnt < k) ? cnt : -1;
    }
    __syncthreads();

    for (int r = wv; r < npg; r += 4) {
        const int nr = mapL[r];
        if (nr < 0) continue;
        const float sc = scoreL[r];
        const float* hr = h + (size_t)(g * npg + r) * H;
        unsigned short* arow = Aout + (size_t)(g * k + nr) * 384;
        #pragma unroll
        for (int half = 0; half < 2; ++half) {
            const int c = ln + half * 64;
            const float y = fmaxf(gmL[c] * (hr[c] - muL[c]) * rsL[c] + btL[c], 0.f) * sc;
            const unsigned short hb = bf16_rne(y);
            const unsigned short lb = bf16_rne(y - bf16_to_f32(hb));
            arow[c] = hb; arow[128 + c] = hb; arow[256 + c] = lb;
        }
    }

    {
        const int e = g * EPG + tid;   // tid in [0,256)
        const int s = esrc_in[e];
        int ns = -1, nd = -1;
        if (s >= 0) {
            const int ms = mapL[s - g * npg];
            const int md = mapL[edst_in[e] - g * npg];
            if (ms >= 0 && md >= 0) { ns = g * k + ms; nd = g * k + md; }
        }
        esrc_out[e] = ns; edst_out[e] = nd;
    }
}

// ---------------------------------------------------------------------------
// fused_pool_final: stage-3 pool (npg=32,k=16) + mean-pool + MLP + sigmoid.
// (unchanged baseline)
// ---------------------------------------------------------------------------
__global__ __launch_bounds__(256)
void fused_pool_final(const float* __restrict__ h,
                      const float* __restrict__ gsum, const float* __restrict__ gsumsq,
                      float n_f,
                      const float* __restrict__ gamma, const float* __restrict__ beta,
                      const float* __restrict__ pw,
                      const float* __restrict__ lin1_w, const float* __restrict__ lin1_b,
                      const float* __restrict__ lin2_w, const float* __restrict__ lin2_b,
                      float* __restrict__ out)
{
    const int g   = blockIdx.x;
    const int tid = threadIdx.x;
    const int wv  = tid >> 6;
    const int ln  = tid & 63;
    const int npg = 32, k = 16;

    __shared__ float muL[128], rsL[128], gmL[128], btL[128], pwL[128];
    __shared__ float scoreL[32], red[128], gmean[128], h1c[64];
    __shared__ int   mapL[32];
    __shared__ float sinv;

    if (tid < 128) {
        const float mu  = gsum[tid] / n_f;
        const float var = gsumsq[tid] / n_f - mu * mu;
        muL[tid] = mu;
        rsL[tid] = rsqrtf(var + 1e-5f);
        gmL[tid] = gamma[tid];
        btL[tid] = beta[tid];
        const float p = pw[tid];
        pwL[tid] = p;
        red[tid] = p * p;
    }
    __syncthreads();
    for (int off = 64; off > 0; off >>= 1) {
        if (tid < off) red[tid] += red[tid + off];
        __syncthreads();
    }
    if (tid == 0) sinv = rsqrtf(red[0]);
    __syncthreads();

    for (int r = wv; r < npg; r += 4) {
        const float* hr = h + (size_t)(g * npg + r) * H;
        float p = 0.f;
        #pragma unroll
        for (int half = 0; half < 2; ++half) {
            const int c = ln + half * 64;
            const float y = fmaxf(gmL[c] * (hr[c] - muL[c]) * rsL[c] + btL[c], 0.f);
            p += y * pwL[c];
        }
        #pragma unroll
        for (int off = 32; off > 0; off >>= 1)
            p += __shfl_down(p, off, 64);
        if (ln == 0) scoreL[r] = tanhf(p * sinv);
    }
    __syncthreads();

    if (tid < npg) {
        const float si = scoreL[tid];
        int cnt = 0;
        for (int j = 0; j < npg; ++j) {
            const float sj = scoreL[j];
            cnt += (sj > si) || (sj == si && j < tid);
        }
        mapL[tid] = (cnt < k) ? cnt : -1;
    }
    __syncthreads();

    if (tid < 128) {
        float acc = 0.f;
        for (int r = 0; r < npg; ++r) {
            if (mapL[r] < 0) continue;
            const float hv = h[(size_t)(g * npg + r) * H + tid];
            const float y  = fmaxf(gmL[tid] * (hv - muL[tid]) * rsL[tid] + btL[tid], 0.f);
            acc += y * scoreL[r];
        }
        gmean[tid] = acc * (1.0f / 16.0f);
    }
    __syncthreads();

    if (tid < 64) {
        float acc = lin1_b[tid];
        for (int o = 0; o < 128; ++o) acc += gmean[o] * lin1_w[o * 64 + tid];
        h1c[tid] = fmaxf(acc, 0.f);
    }
    __syncthreads();
    if (tid == 0) {
        float z = lin2_b[0];
        for (int j = 0; j < 64; ++j) z += h1c[j] * lin2_w[j];
        out[g] = 1.0f / (1.0f + expf(-z));
    }
}

extern "C" void kernel_launch(void* const* d_in, const int* in_sizes, int n_in,
                              void* d_out, int out_size, void* d_ws, size_t ws_size,
                              hipStream_t stream)
{
    const float* x        = (const float*)d_in[0];
    const int*   ei       = (const int*)  d_in[1];
    const float* eattr    = (const float*)d_in[2];
    const float* nn1_w    = (const float*)d_in[4];
    const float* nn1_b    = (const float*)d_in[5];
    const float* root1    = (const float*)d_in[6];
    const float* bias1    = (const float*)d_in[7];
    const float* nn2_w    = (const float*)d_in[8];
    const float* nn2_b    = (const float*)d_in[9];
    const float* root2    = (const float*)d_in[10];
    const float* bias2    = (const float*)d_in[11];
    const float* nn3_w    = (const float*)d_in[12];
    const float* nn3_b    = (const float*)d_in[13];
    const float* root3    = (const float*)d_in[14];
    const float* bias3    = (const float*)d_in[15];
    const float* gamma1   = (const float*)d_in[16];
    const float* beta1    = (const float*)d_in[17];
    const float* gamma2   = (const float*)d_in[18];
    const float* beta2    = (const float*)d_in[19];
    const float* gamma3   = (const float*)d_in[20];
    const float* beta3    = (const float*)d_in[21];
    const float* pw1      = (const float*)d_in[22];
    const float* pw2      = (const float*)d_in[23];
    const float* pw3      = (const float*)d_in[24];
    const float* lin1_w   = (const float*)d_in[25];
    const float* lin1_b   = (const float*)d_in[26];
    const float* lin2_w   = (const float*)d_in[27];
    const float* lin2_b   = (const float*)d_in[28];

    const int* ei_src = ei;
    const int* ei_dst = ei + E_TOT;

    char* wp = (char*)d_ws;
    auto alloc = [&](size_t bytes) { char* p = wp; wp += (bytes + 255) & ~(size_t)255; return p; };
    float* h1   = (float*)alloc(4096 * 128 * 4);
    float* h2   = (float*)alloc(2048 * 128 * 4);
    float* h3   = (float*)alloc(1024 * 128 * 4);
    int*   src1 = (int*)alloc(E_TOT * 4);
    int*   dst1 = (int*)alloc(E_TOT * 4);
    int*   src2 = (int*)alloc(E_TOT * 4);
    int*   dst2 = (int*)alloc(E_TOT * 4);
    float* stats = (float*)alloc(6 * 128 * 4);
    unsigned short* A2   = (unsigned short*)alloc((size_t)2048 * 384 * 2);
    unsigned short* A3   = (unsigned short*)alloc((size_t)1024 * 384 * 2);
    unsigned short* Bt1n = (unsigned short*)alloc((size_t)128 * TROW1 * 2);
    unsigned short* Bt2  = (unsigned short*)alloc((size_t)4352 * 384 * 2);
    unsigned short* Bt3  = (unsigned short*)alloc((size_t)4352 * 384 * 2);
    unsigned short* T1   = (unsigned short*)alloc((size_t)4096 * TROW1 * 2);   // 35.7 MB
    float* hpart = (float*)alloc((size_t)KSPLIT1 * 4096 * 128 * 4);            // 25 MB
    float* Ybuf = (float*)alloc((size_t)2048 * YCOLS * 4);   // stages 2,3 only

    // ---- ALL preprocessing + stats zeroing: ONE dispatch ----
    prep_all<<<562, 256, 0, stream>>>(x, eattr, ei_src, ei_dst,
                                      nn1_w, nn1_b, root1,
                                      nn2_w, nn2_b, root2,
                                      nn3_w, nn3_b, root3,
                                      Bt1n, Bt2, Bt3, T1, stats);

    // ---- Stage 1: k-split GEMM + fused reduce+stats + pool ----
    hgemm1<<<dim3(32, KSPLIT1), 256, 0, stream>>>(T1, Bt1n, bias1, hpart);
    bn_reduce1<<<256, 256, 0, stream>>>(hpart, h1, stats, stats + 128);
    fused_pool<<<NB, 256, 0, stream>>>(h1, stats, stats + 128, 4096.0f,
                                       gamma1, beta1, pw1, 128, 64,
                                       ei_src, ei_dst, src1, dst1, A2);

    // ---- Stage 2 (unchanged baseline) ----
    ygemm_mfma<384><<<dim3(16, NDT), 256, 0, stream>>>(A2, Bt2, Ybuf, bias2, h2);
    contract_edges<<<E_TOT / 8, 256, 0, stream>>>(Ybuf, eattr, src1, dst1, h2);
    bn_stats<<<64, 256, 0, stream>>>(h2, 2048, stats + 256, stats + 384);
    fused_pool<<<NB, 256, 0, stream>>>(h2, stats + 256, stats + 384, 2048.0f,
                                       gamma2, beta2, pw2, 64, 32,
                                       src1, dst1, src2, dst2, A3);

    // ---- Stage 3 (unchanged baseline) ----
    ygemm_mfma<384><<<dim3(8, NDT), 256, 0, stream>>>(A3, Bt3, Ybuf, bias3, h3);
    contract_edges<<<E_TOT / 8, 256, 0, stream>>>(Ybuf, eattr, src2, dst2, h3);
    bn_stats<<<64, 256, 0, stream>>>(h3, 1024, stats + 512, stats + 640);
    fused_pool_final<<<NB, 256, 0, stream>>>(h3, stats + 512, stats + 640, 1024.0f,
                                             gamma3, beta3, pw3,
                                             lin1_w, lin1_b, lin2_w, lin2_b,
                                             (float*)d_out);
}